// Round 2
// baseline (939.591 us; speedup 1.0000x reference)
//
#include <hip/hip_runtime.h>
#include <cfloat>

// Problem constants
// z:   [16, 64, 32, 32] f32   -> N = 16384 rows of dim 64 (row n = b*1024 + h*32 + w)
// emb: [8192, 64] f32
// out (f32): quantized [1048576] | loss [1] | entropy_aux [1] | min_indices [16384]

#define KCODES 8192
#define DDIM 64
#define NPTS 16384

// ws layout (bytes):
//   e2      [0      , 32768)   f32[8192]   (numpy-pairwise ||e_k||^2)
//   invZ    [32768  , 98304)   f32[16384]
//   minidx  [98304  , 163840)  int32[16384]
//   avg_acc [163840 , 196608)  f32[8192]   (zeroed each launch)
//   pse_sum 196608 (double)                (zeroed each launch)
//   loss_sum 196616 (double)               (zeroed each launch)

// ||e_k||^2 with numpy's exact pairwise-8 reduction order and rounding
// (no FMA contraction: __fmul_rn/__fadd_rn).
__global__ __launch_bounds__(256) void k_e2(const float* __restrict__ emb,
                                            float* __restrict__ e2) {
    const int k = blockIdx.x * 256 + threadIdx.x;
    const float* row = emb + k * 64;
    float r8[8];
#pragma unroll
    for (int j = 0; j < 8; ++j) {
        float v = row[j];
        r8[j] = __fmul_rn(v, v);
    }
#pragma unroll
    for (int i = 8; i < 64; i += 8)
#pragma unroll
        for (int j = 0; j < 8; ++j) {
            float v = row[i + j];
            r8[j] = __fadd_rn(r8[j], __fmul_rn(v, v));
        }
    float s01 = __fadd_rn(r8[0], r8[1]);
    float s23 = __fadd_rn(r8[2], r8[3]);
    float s45 = __fadd_rn(r8[4], r8[5]);
    float s67 = __fadd_rn(r8[6], r8[7]);
    e2[k] = __fadd_rn(__fadd_rn(s01, s23), __fadd_rn(s45, s67));
}

// Kernel 1: per-row (n-major) pass. 64 rows per block, sweep all 8192 codes.
// Argmin is done on the f32-rounding-emulated d = fl(fl(zz+ee) - fl(2*s))
// (matches the numpy reference's rounding at magnitude ~64, first-occurrence
// tiebreak). Softmax stats use the well-conditioned r = ee - 2s.
__global__ __launch_bounds__(256) void k_rowstats(
    const float* __restrict__ z, const float* __restrict__ emb,
    const float* __restrict__ e2, float* __restrict__ invZ,
    int* __restrict__ minidx, float* __restrict__ out_idx,
    double* __restrict__ pse_sum)
{
    __shared__ float ztT[64][68];    // [d][row]
    __shared__ float embT[65][132];  // [d][k_local], row 64 = e2 tile
    __shared__ float zzrow[64];      // numpy-pairwise ||z_n||^2
    const int tid = threadIdx.x;
    const int n0 = blockIdx.x * 64;

    { // load z tile: ztT[c][r] = z[(b*64+c)*1024 + hw0 + r]
        const int c = tid >> 2;
        const int r4 = (tid & 3) * 16;
        const float* src = z + ((n0 >> 10) * 64 + c) * 1024 + (n0 & 1023) + r4;
#pragma unroll
        for (int q = 0; q < 4; ++q) {
            float4 v = ((const float4*)src)[q];
            *(float4*)&ztT[c][r4 + 4 * q] = v;
        }
    }
    __syncthreads();

    if (tid < 64) { // numpy pairwise-8 sum of squares for row tid
        float r8[8];
#pragma unroll
        for (int j = 0; j < 8; ++j) {
            float v = ztT[j][tid];
            r8[j] = __fmul_rn(v, v);
        }
#pragma unroll
        for (int i = 8; i < 64; i += 8)
#pragma unroll
            for (int j = 0; j < 8; ++j) {
                float v = ztT[i + j][tid];
                r8[j] = __fadd_rn(r8[j], __fmul_rn(v, v));
            }
        float s01 = __fadd_rn(r8[0], r8[1]);
        float s23 = __fadd_rn(r8[2], r8[3]);
        float s45 = __fadd_rn(r8[4], r8[5]);
        float s67 = __fadd_rn(r8[6], r8[7]);
        zzrow[tid] = __fadd_rn(__fadd_rn(s01, s23), __fadd_rn(s45, s67));
    }

    const int ty = tid >> 4, tx = tid & 15;
    float Zs[4] = {0.f, 0.f, 0.f, 0.f};
    float S1[4] = {0.f, 0.f, 0.f, 0.f};
    float dmin[4] = {FLT_MAX, FLT_MAX, FLT_MAX, FLT_MAX};
    int imin[4] = {0, 0, 0, 0};
    float zz4[4];

    for (int kt = 0; kt < 64; ++kt) {
        const int k0 = kt * 128;
        __syncthreads();  // protect embT from previous readers
        { // load emb tile transposed
            const int ki = tid >> 1;
            const int d0 = (tid & 1) * 32;
            const float* src = emb + (k0 + ki) * 64 + d0;
#pragma unroll
            for (int q = 0; q < 8; ++q) {
                float4 v = ((const float4*)src)[q];
                embT[d0 + 4 * q + 0][ki] = v.x;
                embT[d0 + 4 * q + 1][ki] = v.y;
                embT[d0 + 4 * q + 2][ki] = v.z;
                embT[d0 + 4 * q + 3][ki] = v.w;
            }
            if (tid < 128) embT[64][tid] = e2[k0 + tid];
        }
        __syncthreads();
        if (kt == 0) {
#pragma unroll
            for (int i = 0; i < 4; ++i) zz4[i] = zzrow[ty * 4 + i];
        }

        float acc[4][8];
#pragma unroll
        for (int i = 0; i < 4; ++i)
#pragma unroll
            for (int j = 0; j < 8; ++j) acc[i][j] = 0.f;

#pragma unroll 8
        for (int d = 0; d < 64; ++d) {
            float4 a = *(const float4*)&ztT[d][ty * 4];
            float4 b0 = *(const float4*)&embT[d][tx * 8];
            float4 b1 = *(const float4*)&embT[d][tx * 8 + 4];
            float av[4] = {a.x, a.y, a.z, a.w};
            float bv[8] = {b0.x, b0.y, b0.z, b0.w, b1.x, b1.y, b1.z, b1.w};
#pragma unroll
            for (int i = 0; i < 4; ++i)
#pragma unroll
                for (int j = 0; j < 8; ++j)
                    acc[i][j] = fmaf(av[i], bv[j], acc[i][j]);
        }

#pragma unroll
        for (int j = 0; j < 8; ++j) {
            const float e2v = embT[64][tx * 8 + j];
            const int kk = k0 + tx * 8 + j;
#pragma unroll
            for (int i = 0; i < 4; ++i) {
                // softmax path (shift-invariant, well-conditioned)
                float r = fmaf(-2.f, acc[i][j], e2v);
                float aa = -100.f * r;
                float ex = __expf(aa);
                Zs[i] += ex;
                S1[i] = fmaf(aa, ex, S1[i]);
                // argmin path: emulate numpy f32 rounding of
                // d = (zz + ee) - 2*s  (adds at magnitude ~64, no contraction)
                float dnp = __fsub_rn(__fadd_rn(zz4[i], e2v),
                                      __fmul_rn(2.f, acc[i][j]));
                if (dnp < dmin[i]) { dmin[i] = dnp; imin[i] = kk; }
            }
        }
    }

    // reduce across the 16 tx lanes sharing each row group (lex tiebreak: min d, then min idx)
#pragma unroll
    for (int m = 1; m < 16; m <<= 1) {
#pragma unroll
        for (int i = 0; i < 4; ++i) {
            float r2 = __shfl_xor(dmin[i], m, 16);
            int i2 = __shfl_xor(imin[i], m, 16);
            float Z2 = __shfl_xor(Zs[i], m, 16);
            float s2 = __shfl_xor(S1[i], m, 16);
            if (r2 < dmin[i] || (r2 == dmin[i] && i2 < imin[i])) { dmin[i] = r2; imin[i] = i2; }
            Zs[i] += Z2;
            S1[i] += s2;
        }
    }
    if (tx == 0) {
        double h = 0.0;
#pragma unroll
        for (int i = 0; i < 4; ++i) {
            int n = n0 + ty * 4 + i;
            minidx[n] = imin[i];
            out_idx[n] = (float)imin[i];
            float iz = 1.0f / Zs[i];
            invZ[n] = iz;
            h += (double)(logf(Zs[i]) - S1[i] * iz);
        }
        atomicAdd(pse_sum, h);
    }
}

// Kernel 2: k-major pass. Block owns a 128-wide k tile and a 4096-row n range;
// accumulates sum_n exp(-100*r_nk) * invZ_n into avg_acc[k].
__global__ __launch_bounds__(256) void k_avgprob(
    const float* __restrict__ z, const float* __restrict__ emb,
    const float* __restrict__ e2, const float* __restrict__ invZ,
    float* __restrict__ avg_acc)
{
    __shared__ float ztT[64][68];
    __shared__ float embT[65][132];
    __shared__ float izrow[64];
    __shared__ float accsh[128];
    const int tid = threadIdx.x;
    const int k0 = (blockIdx.x & 63) * 128;
    const int nbase = (blockIdx.x >> 6) * 4096;

    { // load emb tile once
        const int ki = tid >> 1;
        const int d0 = (tid & 1) * 32;
        const float* src = emb + (k0 + ki) * 64 + d0;
#pragma unroll
        for (int q = 0; q < 8; ++q) {
            float4 v = ((const float4*)src)[q];
            embT[d0 + 4 * q + 0][ki] = v.x;
            embT[d0 + 4 * q + 1][ki] = v.y;
            embT[d0 + 4 * q + 2][ki] = v.z;
            embT[d0 + 4 * q + 3][ki] = v.w;
        }
        if (tid < 128) { embT[64][tid] = e2[k0 + tid]; accsh[tid] = 0.f; }
    }

    const int ty = tid >> 4, tx = tid & 15;
    float e2v[8];
    float acc[8] = {0.f, 0.f, 0.f, 0.f, 0.f, 0.f, 0.f, 0.f};

    for (int nt = 0; nt < 64; ++nt) {
        const int n0 = nbase + nt * 64;
        __syncthreads();  // previous iter done reading ztT (and embT writes at nt=0)
        {
            const int c = tid >> 2;
            const int r4 = (tid & 3) * 16;
            const float* src = z + ((n0 >> 10) * 64 + c) * 1024 + (n0 & 1023) + r4;
#pragma unroll
            for (int q = 0; q < 4; ++q) {
                float4 v = ((const float4*)src)[q];
                *(float4*)&ztT[c][r4 + 4 * q] = v;
            }
        }
        if (tid < 64) izrow[tid] = invZ[n0 + tid];
        __syncthreads();
        if (nt == 0) {
#pragma unroll
            for (int j = 0; j < 8; ++j) e2v[j] = embT[64][tx * 8 + j];
        }

        float tacc[4][8];
#pragma unroll
        for (int i = 0; i < 4; ++i)
#pragma unroll
            for (int j = 0; j < 8; ++j) tacc[i][j] = 0.f;

#pragma unroll 8
        for (int d = 0; d < 64; ++d) {
            float4 a = *(const float4*)&ztT[d][ty * 4];
            float4 b0 = *(const float4*)&embT[d][tx * 8];
            float4 b1 = *(const float4*)&embT[d][tx * 8 + 4];
            float av[4] = {a.x, a.y, a.z, a.w};
            float bv[8] = {b0.x, b0.y, b0.z, b0.w, b1.x, b1.y, b1.z, b1.w};
#pragma unroll
            for (int i = 0; i < 4; ++i)
#pragma unroll
                for (int j = 0; j < 8; ++j)
                    tacc[i][j] = fmaf(av[i], bv[j], tacc[i][j]);
        }

#pragma unroll
        for (int i = 0; i < 4; ++i) {
            float iz = izrow[ty * 4 + i];
#pragma unroll
            for (int j = 0; j < 8; ++j) {
                float r = fmaf(-2.f, tacc[i][j], e2v[j]);
                acc[j] = fmaf(__expf(-100.f * r), iz, acc[j]);
            }
        }
    }

    __syncthreads();
#pragma unroll
    for (int j = 0; j < 8; ++j) atomicAdd(&accsh[tx * 8 + j], acc[j]);
    __syncthreads();
    if (tid < 128) atomicAdd(&avg_acc[k0 + tid], accsh[tid]);
}

// Kernel 3: gather quantized output (b c h w layout == z layout) + loss sum.
__global__ __launch_bounds__(256) void k_quant(
    const float* __restrict__ z, const float* __restrict__ emb,
    const int* __restrict__ minidx, float* __restrict__ out,
    double* __restrict__ loss_sum)
{
    const int o = blockIdx.x * 256 + threadIdx.x;
    const int n = ((o >> 16) << 10) + (o & 1023);
    const int c = (o >> 10) & 63;
    const int idx = minidx[n];
    const float e = emb[idx * 64 + c];
    const float zv = z[o];
    out[o] = e;
    float d = e - zv;
    float sq = d * d;
#pragma unroll
    for (int m = 32; m > 0; m >>= 1) sq += __shfl_xor(sq, m, 64);
    if ((threadIdx.x & 63) == 0) atomicAdd(loss_sum, (double)sq);
}

__global__ __launch_bounds__(256) void k_final(
    const float* __restrict__ avg_acc, const double* __restrict__ pse_sum,
    const double* __restrict__ loss_sum, float* __restrict__ out)
{
    __shared__ double red[256];
    const int tid = threadIdx.x;
    double local = 0.0;
    for (int k = tid; k < KCODES; k += 256) {
        float p = avg_acc[k] * (1.0f / 16384.0f);
        float cl = fmaxf(p, 1e-5f);
        local += (double)(-p * logf(cl));
    }
    red[tid] = local;
    __syncthreads();
    for (int s = 128; s > 0; s >>= 1) {
        if (tid < s) red[tid] += red[tid + s];
        __syncthreads();
    }
    if (tid == 0) {
        double ce = red[0];
        double pse = pse_sum[0] / 16384.0;
        out[1048576] = (float)(1.25 * loss_sum[0] / 1048576.0);
        out[1048577] = (float)(pse - ce);
    }
}

extern "C" void kernel_launch(void* const* d_in, const int* in_sizes, int n_in,
                              void* d_out, int out_size, void* d_ws, size_t ws_size,
                              hipStream_t stream) {
    const float* z = (const float*)d_in[0];
    const float* emb = (const float*)d_in[1];
    float* out = (float*)d_out;
    char* ws = (char*)d_ws;
    float* e2 = (float*)(ws);
    float* invZ = (float*)(ws + 32768);
    int* minidx = (int*)(ws + 98304);
    float* avg_acc = (float*)(ws + 163840);
    double* pse_sum = (double*)(ws + 196608);
    double* loss_sum = (double*)(ws + 196616);

    // zero the accumulators every launch (no cross-replay state)
    hipMemsetAsync(ws + 163840, 0, 32768 + 16, stream);

    k_e2<<<32, 256, 0, stream>>>(emb, e2);
    k_rowstats<<<256, 256, 0, stream>>>(z, emb, e2, invZ, minidx, out + 1048578, pse_sum);
    k_avgprob<<<256, 256, 0, stream>>>(z, emb, e2, invZ, avg_acc);
    k_quant<<<4096, 256, 0, stream>>>(z, emb, minidx, out, loss_sum);
    k_final<<<1, 256, 0, stream>>>(avg_acc, pse_sum, loss_sum, out);
}

// Round 3
// 432.524 us; speedup vs baseline: 2.1723x; 2.1723x over previous
//
#include <hip/hip_runtime.h>
#include <cfloat>

// z:   [16, 64, 32, 32] f32 -> N = 16384 rows of dim 64 (row n = b*1024 + hw)
// emb: [8192, 64] f32
// out (f32): quantized [1048576] | loss [1] | entropy_aux [1] | min_indices [16384]
//
// s = z.e via 4-term bf16-split MFMA (zh+zl)(eh+el), f32 accumulate ->
// error ~1e-10 vs numpy f32 einsum (same class as the fmaf chain that passed).
// argmin on numpy-rounding-emulated d = fl(fl(zz+ee) - fl(2s)).

typedef __attribute__((ext_vector_type(8))) short short8v;   // 8 bf16
typedef __attribute__((ext_vector_type(4))) float f32x4;

#define C100L2E 144.26950408889634f   // 100*log2(e)
#define C200L2E 288.53900817779268f   // 200*log2(e)
#define LN2 0.6931471805599453

__device__ __forceinline__ unsigned short f2bf_rne(float f) {
    unsigned u = __float_as_uint(f);
    u = (u + 0x7fffu + ((u >> 16) & 1u)) >> 16;
    return (unsigned short)u;
}

// ws layout (bytes):
//   e2       [0, 32768)        f32[8192] (numpy-pairwise ||e_k||^2)
//   invZ     [32768, 98304)    f32[16384]
//   minidx   [98304, 163840)   i32[16384]
//   avg_acc  [163840, 196608)  f32[8192]  (zeroed each launch)
//   pse_sum  196608 dbl, loss_sum 196616 dbl (zeroed each launch)
//   Zpart    [196624, +262144) f32[4][16384]
//   S1part   next 262144
//   dmpart   next 262144
//   impart   next 262144

__global__ __launch_bounds__(256) void k_e2(const float* __restrict__ emb,
                                            float* __restrict__ e2) {
    const int k = blockIdx.x * 256 + threadIdx.x;
    const float* row = emb + k * 64;
    float r8[8];
#pragma unroll
    for (int j = 0; j < 8; ++j) { float v = row[j]; r8[j] = __fmul_rn(v, v); }
#pragma unroll
    for (int i = 8; i < 64; i += 8)
#pragma unroll
        for (int j = 0; j < 8; ++j) {
            float v = row[i + j];
            r8[j] = __fadd_rn(r8[j], __fmul_rn(v, v));
        }
    float s01 = __fadd_rn(r8[0], r8[1]), s23 = __fadd_rn(r8[2], r8[3]);
    float s45 = __fadd_rn(r8[4], r8[5]), s67 = __fadd_rn(r8[6], r8[7]);
    e2[k] = __fadd_rn(__fadd_rn(s01, s23), __fadd_rn(s45, s67));
}

// ---- pass 1: per-row stats (argmin, Z, S1') over a 2048-wide k split ----
__global__ __launch_bounds__(256) void k_pass1(
    const float* __restrict__ z, const float* __restrict__ emb,
    const float* __restrict__ e2,
    float* __restrict__ Zpart, float* __restrict__ S1part,
    float* __restrict__ dmpart, int* __restrict__ impart)
{
    __shared__ __align__(16) char smem[34816];
    __shared__ float zzsh[128];
    float (*zt)[136] = (float (*)[136])smem;       // phase A: z staging, d-major
    short* ehb = (short*)smem;                      // phase B: e-hi bf16 [128][64] swizzled
    short* elb = (short*)(smem + 16384);            //          e-lo bf16
    float* e2s = (float*)(smem + 32768);            //          e2 tile [128]

    const int tid = threadIdx.x;
    const int panel = blockIdx.x >> 2;
    const int ks = blockIdx.x & 3;
    const int n0 = panel * 128;

    { // stage z panel: zt[d][r] = z[(n0>>10)*65536 + d*1024 + (n0&1023) + r]
        const int c = tid >> 2, q = tid & 3;
        const float* src = z + ((n0 >> 10) * 64 + c) * 1024 + (n0 & 1023) + q * 32;
#pragma unroll
        for (int i = 0; i < 8; ++i) {
            float4 v = ((const float4*)src)[i];
            *(float4*)&zt[c][q * 32 + 4 * i] = v;
        }
    }
    __syncthreads();
    if (tid < 128) { // numpy pairwise-8 ||z||^2
        float r8[8];
#pragma unroll
        for (int j = 0; j < 8; ++j) { float v = zt[j][tid]; r8[j] = __fmul_rn(v, v); }
#pragma unroll
        for (int i = 8; i < 64; i += 8)
#pragma unroll
            for (int j = 0; j < 8; ++j) {
                float v = zt[i + j][tid];
                r8[j] = __fadd_rn(r8[j], __fmul_rn(v, v));
            }
        float s01 = __fadd_rn(r8[0], r8[1]), s23 = __fadd_rn(r8[2], r8[3]);
        float s45 = __fadd_rn(r8[4], r8[5]), s67 = __fadd_rn(r8[6], r8[7]);
        zzsh[tid] = __fadd_rn(__fadd_rn(s01, s23), __fadd_rn(s45, s67));
    }

    const int ln = tid & 63, wv = tid >> 6;
    const int lr = ln & 15, lg = ln >> 4;

    // A-frags in registers for the whole kernel: rows wv*32+m*16+lr, k=s*32+lg*8+j
    short8v Ah[2][2], Al[2][2];
#pragma unroll
    for (int m = 0; m < 2; ++m)
#pragma unroll
        for (int s = 0; s < 2; ++s) {
            const int row = wv * 32 + m * 16 + lr;
            const int db = s * 32 + lg * 8;
#pragma unroll
            for (int j = 0; j < 8; ++j) {
                float f = zt[db + j][row];
                unsigned short hb = f2bf_rne(f);
                float hf = __uint_as_float((unsigned)hb << 16);
                unsigned short lb = f2bf_rne(f - hf);
                Ah[m][s][j] = (short)hb;
                Al[m][s][j] = (short)lb;
            }
        }
    __syncthreads();   // zt reads + zzsh writes done; smem free for e tiles

    float zzr[2][4];
#pragma unroll
    for (int m = 0; m < 2; ++m)
#pragma unroll
        for (int rg = 0; rg < 4; ++rg)
            zzr[m][rg] = zzsh[wv * 32 + m * 16 + lg * 4 + rg];

    float Zp[2][4], S1p[2][4], dmin[2][4];
    int imin[2][4];
#pragma unroll
    for (int m = 0; m < 2; ++m)
#pragma unroll
        for (int rg = 0; rg < 4; ++rg) {
            Zp[m][rg] = 0.f; S1p[m][rg] = 0.f; dmin[m][rg] = FLT_MAX; imin[m][rg] = 0;
        }

    for (int it = 0; it < 16; ++it) {
        const int kbase = ks * 2048 + it * 128;
        { // stage e tile (bf16 hi/lo, XOR-swizzled rows)
            const int r = tid >> 1, dh = tid & 1;
            const float* esrc = emb + (kbase + r) * 64 + dh * 32;
            float fv[32];
#pragma unroll
            for (int i = 0; i < 8; ++i) {
                float4 v = ((const float4*)esrc)[i];
                fv[4 * i] = v.x; fv[4 * i + 1] = v.y; fv[4 * i + 2] = v.z; fv[4 * i + 3] = v.w;
            }
            unsigned short hb[32], lb[32];
#pragma unroll
            for (int i = 0; i < 32; ++i) {
                hb[i] = f2bf_rne(fv[i]);
                float hf = __uint_as_float((unsigned)hb[i] << 16);
                lb[i] = f2bf_rne(fv[i] - hf);
            }
            const int sw = (r & 7) << 4;
#pragma unroll
            for (int c = 0; c < 4; ++c) {
                const int byt = (r * 128 + dh * 64 + c * 16) ^ sw;
                short8v hv, lv;
#pragma unroll
                for (int e = 0; e < 8; ++e) { hv[e] = (short)hb[c * 8 + e]; lv[e] = (short)lb[c * 8 + e]; }
                *(short8v*)((char*)ehb + byt) = hv;
                *(short8v*)((char*)elb + byt) = lv;
            }
            if (tid < 128) e2s[tid] = e2[kbase + tid];
        }
        __syncthreads();

        f32x4 acc[2][8];
#pragma unroll
        for (int m = 0; m < 2; ++m)
#pragma unroll
            for (int f = 0; f < 8; ++f) {
                f32x4 zz4 = {0.f, 0.f, 0.f, 0.f};
                acc[m][f] = zz4;
            }

#pragma unroll
        for (int f = 0; f < 8; ++f) {
            const int rr = f * 16 + lr;
            const int sw2 = (rr & 7) << 4;
            short8v Bh[2], Bl[2];
#pragma unroll
            for (int s = 0; s < 2; ++s) {
                const int byt = (rr * 128 + s * 64 + lg * 16) ^ sw2;
                Bh[s] = *(const short8v*)((const char*)ehb + byt);
                Bl[s] = *(const short8v*)((const char*)elb + byt);
            }
#pragma unroll
            for (int s = 0; s < 2; ++s)
#pragma unroll
                for (int m = 0; m < 2; ++m) {
                    acc[m][f] = __builtin_amdgcn_mfma_f32_16x16x32_bf16(Ah[m][s], Bh[s], acc[m][f], 0, 0, 0);
                    acc[m][f] = __builtin_amdgcn_mfma_f32_16x16x32_bf16(Ah[m][s], Bl[s], acc[m][f], 0, 0, 0);
                    acc[m][f] = __builtin_amdgcn_mfma_f32_16x16x32_bf16(Al[m][s], Bh[s], acc[m][f], 0, 0, 0);
                    acc[m][f] = __builtin_amdgcn_mfma_f32_16x16x32_bf16(Al[m][s], Bl[s], acc[m][f], 0, 0, 0);
                }
        }

#pragma unroll
        for (int f = 0; f < 8; ++f) {
            const float e2v = e2s[f * 16 + lr];
            const float c2 = e2v * C100L2E;
            const int kk = kbase + f * 16 + lr;
#pragma unroll
            for (int m = 0; m < 2; ++m)
#pragma unroll
                for (int rg = 0; rg < 4; ++rg) {
                    const float sdot = acc[m][f][rg];
                    const float t = fmaf(sdot, C200L2E, -c2);   // log2 exp(-100(ee-2s))
                    const float ex = __builtin_amdgcn_exp2f(t);
                    Zp[m][rg] += ex;
                    S1p[m][rg] = fmaf(t, ex, S1p[m][rg]);        // Sigma t*ex (mul ln2 later)
                    const float dnp = __fsub_rn(__fadd_rn(zzr[m][rg], e2v),
                                                __fmul_rn(2.f, sdot));
                    if (dnp < dmin[m][rg]) { dmin[m][rg] = dnp; imin[m][rg] = kk; }
                }
        }
        __syncthreads();
    }

    // reduce across the 16 lr lanes (cols); lex tiebreak (min d, then min idx)
#pragma unroll
    for (int msk = 1; msk < 16; msk <<= 1) {
#pragma unroll
        for (int m = 0; m < 2; ++m)
#pragma unroll
            for (int rg = 0; rg < 4; ++rg) {
                float d2 = __shfl_xor(dmin[m][rg], msk, 16);
                int i2 = __shfl_xor(imin[m][rg], msk, 16);
                float Z2 = __shfl_xor(Zp[m][rg], msk, 16);
                float s2 = __shfl_xor(S1p[m][rg], msk, 16);
                if (d2 < dmin[m][rg] || (d2 == dmin[m][rg] && i2 < imin[m][rg])) {
                    dmin[m][rg] = d2; imin[m][rg] = i2;
                }
                Zp[m][rg] += Z2;
                S1p[m][rg] += s2;
            }
    }
    if (lr == 0) {
#pragma unroll
        for (int m = 0; m < 2; ++m)
#pragma unroll
            for (int rg = 0; rg < 4; ++rg) {
                const int n = n0 + wv * 32 + m * 16 + lg * 4 + rg;
                Zpart[ks * 16384 + n] = Zp[m][rg];
                S1part[ks * 16384 + n] = S1p[m][rg];
                dmpart[ks * 16384 + n] = dmin[m][rg];
                impart[ks * 16384 + n] = imin[m][rg];
            }
    }
}

__global__ __launch_bounds__(256) void k_rowred(
    const float* __restrict__ Zpart, const float* __restrict__ S1part,
    const float* __restrict__ dmpart, const int* __restrict__ impart,
    float* __restrict__ invZ, int* __restrict__ minidx,
    float* __restrict__ out_idx, double* __restrict__ pse_sum)
{
    const int n = blockIdx.x * 256 + threadIdx.x;
    float Z = __fadd_rn(__fadd_rn(Zpart[n], Zpart[16384 + n]),
                        __fadd_rn(Zpart[32768 + n], Zpart[49152 + n]));
    float S1 = __fadd_rn(__fadd_rn(S1part[n], S1part[16384 + n]),
                         __fadd_rn(S1part[32768 + n], S1part[49152 + n]));
    float dm = dmpart[n];
    int im = impart[n];
#pragma unroll
    for (int ksp = 1; ksp < 4; ++ksp) {
        float d2 = dmpart[ksp * 16384 + n];
        int i2 = impart[ksp * 16384 + n];
        if (d2 < dm || (d2 == dm && i2 < im)) { dm = d2; im = i2; }
    }
    minidx[n] = im;
    out_idx[n] = (float)im;
    float iz = 1.0f / Z;
    invZ[n] = iz;
    double h = log((double)Z) - LN2 * (double)S1 * (double)iz;
#pragma unroll
    for (int m = 32; m > 0; m >>= 1) h += __shfl_xor(h, m, 64);
    if ((threadIdx.x & 63) == 0) atomicAdd(pse_sum, h);
}

// ---- pass 2: avg_prob accumulation ----
__global__ __launch_bounds__(256) void k_pass2(
    const float* __restrict__ z, const float* __restrict__ emb,
    const float* __restrict__ e2, const float* __restrict__ invZ,
    float* __restrict__ avg_acc)
{
    __shared__ __align__(16) char smem[34816];
    float (*zt)[136] = (float (*)[136])smem;
    short* ehb = (short*)smem;
    short* elb = (short*)(smem + 16384);
    float* e2s = (float*)(smem + 32768);

    const int tid = threadIdx.x;
    const int panel = blockIdx.x >> 2;
    const int ks = blockIdx.x & 3;
    const int n0 = panel * 128;

    {
        const int c = tid >> 2, q = tid & 3;
        const float* src = z + ((n0 >> 10) * 64 + c) * 1024 + (n0 & 1023) + q * 32;
#pragma unroll
        for (int i = 0; i < 8; ++i) {
            float4 v = ((const float4*)src)[i];
            *(float4*)&zt[c][q * 32 + 4 * i] = v;
        }
    }
    __syncthreads();

    const int ln = tid & 63, wv = tid >> 6;
    const int lr = ln & 15, lg = ln >> 4;

    short8v Ah[2][2], Al[2][2];
#pragma unroll
    for (int m = 0; m < 2; ++m)
#pragma unroll
        for (int s = 0; s < 2; ++s) {
            const int row = wv * 32 + m * 16 + lr;
            const int db = s * 32 + lg * 8;
#pragma unroll
            for (int j = 0; j < 8; ++j) {
                float f = zt[db + j][row];
                unsigned short hb = f2bf_rne(f);
                float hf = __uint_as_float((unsigned)hb << 16);
                unsigned short lb = f2bf_rne(f - hf);
                Ah[m][s][j] = (short)hb;
                Al[m][s][j] = (short)lb;
            }
        }
    __syncthreads();

    float izr[2][4];
#pragma unroll
    for (int m = 0; m < 2; ++m)
#pragma unroll
        for (int rg = 0; rg < 4; ++rg)
            izr[m][rg] = invZ[n0 + wv * 32 + m * 16 + lg * 4 + rg];

    for (int it = 0; it < 16; ++it) {
        const int kbase = ks * 2048 + it * 128;
        {
            const int r = tid >> 1, dh = tid & 1;
            const float* esrc = emb + (kbase + r) * 64 + dh * 32;
            float fv[32];
#pragma unroll
            for (int i = 0; i < 8; ++i) {
                float4 v = ((const float4*)esrc)[i];
                fv[4 * i] = v.x; fv[4 * i + 1] = v.y; fv[4 * i + 2] = v.z; fv[4 * i + 3] = v.w;
            }
            unsigned short hb[32], lb[32];
#pragma unroll
            for (int i = 0; i < 32; ++i) {
                hb[i] = f2bf_rne(fv[i]);
                float hf = __uint_as_float((unsigned)hb[i] << 16);
                lb[i] = f2bf_rne(fv[i] - hf);
            }
            const int sw = (r & 7) << 4;
#pragma unroll
            for (int c = 0; c < 4; ++c) {
                const int byt = (r * 128 + dh * 64 + c * 16) ^ sw;
                short8v hv, lv;
#pragma unroll
                for (int e = 0; e < 8; ++e) { hv[e] = (short)hb[c * 8 + e]; lv[e] = (short)lb[c * 8 + e]; }
                *(short8v*)((char*)ehb + byt) = hv;
                *(short8v*)((char*)elb + byt) = lv;
            }
            if (tid < 128) e2s[tid] = e2[kbase + tid];
        }
        __syncthreads();

        f32x4 acc[2][8];
#pragma unroll
        for (int m = 0; m < 2; ++m)
#pragma unroll
            for (int f = 0; f < 8; ++f) {
                f32x4 zz4 = {0.f, 0.f, 0.f, 0.f};
                acc[m][f] = zz4;
            }

#pragma unroll
        for (int f = 0; f < 8; ++f) {
            const int rr = f * 16 + lr;
            const int sw2 = (rr & 7) << 4;
            short8v Bh[2], Bl[2];
#pragma unroll
            for (int s = 0; s < 2; ++s) {
                const int byt = (rr * 128 + s * 64 + lg * 16) ^ sw2;
                Bh[s] = *(const short8v*)((const char*)ehb + byt);
                Bl[s] = *(const short8v*)((const char*)elb + byt);
            }
#pragma unroll
            for (int s = 0; s < 2; ++s)
#pragma unroll
                for (int m = 0; m < 2; ++m) {
                    acc[m][f] = __builtin_amdgcn_mfma_f32_16x16x32_bf16(Ah[m][s], Bh[s], acc[m][f], 0, 0, 0);
                    acc[m][f] = __builtin_amdgcn_mfma_f32_16x16x32_bf16(Ah[m][s], Bl[s], acc[m][f], 0, 0, 0);
                    acc[m][f] = __builtin_amdgcn_mfma_f32_16x16x32_bf16(Al[m][s], Bh[s], acc[m][f], 0, 0, 0);
                    acc[m][f] = __builtin_amdgcn_mfma_f32_16x16x32_bf16(Al[m][s], Bl[s], acc[m][f], 0, 0, 0);
                }
        }

#pragma unroll
        for (int f = 0; f < 8; ++f) {
            const float c2 = e2s[f * 16 + lr] * C100L2E;
            float cs = 0.f;
#pragma unroll
            for (int m = 0; m < 2; ++m)
#pragma unroll
                for (int rg = 0; rg < 4; ++rg) {
                    const float t = fmaf(acc[m][f][rg], C200L2E, -c2);
                    const float ex = __builtin_amdgcn_exp2f(t);
                    cs = fmaf(ex, izr[m][rg], cs);
                }
            cs += __shfl_xor(cs, 16, 64);
            cs += __shfl_xor(cs, 32, 64);
            if (lg == 0) atomicAdd(&avg_acc[kbase + f * 16 + lr], cs);
        }
        __syncthreads();
    }
}

__global__ __launch_bounds__(256) void k_quant(
    const float* __restrict__ z, const float* __restrict__ emb,
    const int* __restrict__ minidx, float* __restrict__ out,
    double* __restrict__ loss_sum)
{
    const int o = blockIdx.x * 256 + threadIdx.x;
    const int n = ((o >> 16) << 10) + (o & 1023);
    const int c = (o >> 10) & 63;
    const int idx = minidx[n];
    const float e = emb[idx * 64 + c];
    const float zv = z[o];
    out[o] = e;
    float d = e - zv;
    float sq = d * d;
#pragma unroll
    for (int m = 32; m > 0; m >>= 1) sq += __shfl_xor(sq, m, 64);
    if ((threadIdx.x & 63) == 0) atomicAdd(loss_sum, (double)sq);
}

__global__ __launch_bounds__(256) void k_final(
    const float* __restrict__ avg_acc, const double* __restrict__ pse_sum,
    const double* __restrict__ loss_sum, float* __restrict__ out)
{
    __shared__ double red[256];
    const int tid = threadIdx.x;
    double local = 0.0;
    for (int k = tid; k < 8192; k += 256) {
        float p = avg_acc[k] * (1.0f / 16384.0f);
        float cl = fmaxf(p, 1e-5f);
        local += (double)(-p * logf(cl));
    }
    red[tid] = local;
    __syncthreads();
    for (int s = 128; s > 0; s >>= 1) {
        if (tid < s) red[tid] += red[tid + s];
        __syncthreads();
    }
    if (tid == 0) {
        double ce = red[0];
        double pse = pse_sum[0] / 16384.0;
        out[1048576] = (float)(1.25 * loss_sum[0] / 1048576.0);
        out[1048577] = (float)(pse - ce);
    }
}

extern "C" void kernel_launch(void* const* d_in, const int* in_sizes, int n_in,
                              void* d_out, int out_size, void* d_ws, size_t ws_size,
                              hipStream_t stream) {
    const float* z = (const float*)d_in[0];
    const float* emb = (const float*)d_in[1];
    float* out = (float*)d_out;
    char* ws = (char*)d_ws;
    float* e2 = (float*)(ws);
    float* invZ = (float*)(ws + 32768);
    int* minidx = (int*)(ws + 98304);
    float* avg_acc = (float*)(ws + 163840);
    double* pse_sum = (double*)(ws + 196608);
    double* loss_sum = (double*)(ws + 196616);
    float* Zpart = (float*)(ws + 196624);
    float* S1part = (float*)(ws + 196624 + 262144);
    float* dmpart = (float*)(ws + 196624 + 524288);
    int* impart = (int*)(ws + 196624 + 786432);

    hipMemsetAsync(ws + 163840, 0, 32768 + 16, stream);

    k_e2<<<32, 256, 0, stream>>>(emb, e2);
    k_pass1<<<512, 256, 0, stream>>>(z, emb, e2, Zpart, S1part, dmpart, impart);
    k_rowred<<<64, 256, 0, stream>>>(Zpart, S1part, dmpart, impart,
                                     invZ, minidx, out + 1048578, pse_sum);
    k_pass2<<<512, 256, 0, stream>>>(z, emb, e2, invZ, avg_acc);
    k_quant<<<4096, 256, 0, stream>>>(z, emb, minidx, out, loss_sum);
    k_final<<<1, 256, 0, stream>>>(avg_acc, pse_sum, loss_sum, out);
}

// Round 4
// 242.080 us; speedup vs baseline: 3.8813x; 1.7867x over previous
//
#include <hip/hip_runtime.h>
#include <cfloat>

// z:   [16, 64, 32, 32] f32 -> N = 16384 rows of dim 64 (row n = b*1024 + hw)
// emb: [8192, 64] f32
// out (f32): quantized [1048576] | loss [1] | entropy_aux [1] | min_indices [16384]
//
// s = z.e via 4-term bf16-split MFMA (zh+zl)(eh+el), f32 accumulate ->
// error ~1e-10 vs numpy f32 einsum. argmin on numpy-rounding-emulated
// d = fl(fl(zz+ee) - fl(2s)).

typedef __attribute__((ext_vector_type(8))) short short8v;   // 8 bf16
typedef __attribute__((ext_vector_type(4))) float f32x4;

#define C100L2E 144.26950408889634f   // 100*log2(e)
#define C200L2E 288.53900817779268f   // 200*log2(e)
#define LN2 0.6931471805599453

__device__ __forceinline__ unsigned short f2bf_rne(float f) {
    unsigned u = __float_as_uint(f);
    u = (u + 0x7fffu + ((u >> 16) & 1u)) >> 16;
    return (unsigned short)u;
}

// ws layout (bytes):
//   e2       [0, 32768)        f32[8192] (numpy-pairwise ||e_k||^2)
//   invZ     [32768, 98304)    f32[16384]
//   minidx   [98304, 163840)   i32[16384]
//   avg_acc  [163840, 196608)  f32[8192]  (zeroed each launch)
//   pse_sum  196608 dbl                   (zeroed each launch)
//   Zpart    [196624, +262144) f32[4][16384]
//   S1part   next 262144
//   dmpart   next 262144
//   impart   next 262144
//   loss_part [1245200, +32768) dbl[4096] (fully rewritten each launch)

__global__ __launch_bounds__(256) void k_e2(const float* __restrict__ emb,
                                            float* __restrict__ e2) {
    const int k = blockIdx.x * 256 + threadIdx.x;
    const float* row = emb + k * 64;
    float r8[8];
#pragma unroll
    for (int j = 0; j < 8; ++j) { float v = row[j]; r8[j] = __fmul_rn(v, v); }
#pragma unroll
    for (int i = 8; i < 64; i += 8)
#pragma unroll
        for (int j = 0; j < 8; ++j) {
            float v = row[i + j];
            r8[j] = __fadd_rn(r8[j], __fmul_rn(v, v));
        }
    float s01 = __fadd_rn(r8[0], r8[1]), s23 = __fadd_rn(r8[2], r8[3]);
    float s45 = __fadd_rn(r8[4], r8[5]), s67 = __fadd_rn(r8[6], r8[7]);
    e2[k] = __fadd_rn(__fadd_rn(s01, s23), __fadd_rn(s45, s67));
}

// ---- pass 1: per-row stats (argmin, Z, S1') over a 2048-wide k split ----
__global__ __launch_bounds__(256) void k_pass1(
    const float* __restrict__ z, const float* __restrict__ emb,
    const float* __restrict__ e2,
    float* __restrict__ Zpart, float* __restrict__ S1part,
    float* __restrict__ dmpart, int* __restrict__ impart)
{
    __shared__ __align__(16) char smem[34816];
    __shared__ float zzsh[128];
    float (*zt)[136] = (float (*)[136])smem;       // phase A: z staging, d-major
    short* ehb = (short*)smem;                      // phase B: e-hi bf16 [128][64] swizzled
    short* elb = (short*)(smem + 16384);            //          e-lo bf16
    float* e2s = (float*)(smem + 32768);            //          e2 tile [128]

    const int tid = threadIdx.x;
    const int panel = blockIdx.x >> 2;
    const int ks = blockIdx.x & 3;
    const int n0 = panel * 128;

    { // stage z panel: zt[d][r]
        const int c = tid >> 2, q = tid & 3;
        const float* src = z + ((n0 >> 10) * 64 + c) * 1024 + (n0 & 1023) + q * 32;
#pragma unroll
        for (int i = 0; i < 8; ++i) {
            float4 v = ((const float4*)src)[i];
            *(float4*)&zt[c][q * 32 + 4 * i] = v;
        }
    }
    __syncthreads();
    if (tid < 128) { // numpy pairwise-8 ||z||^2
        float r8[8];
#pragma unroll
        for (int j = 0; j < 8; ++j) { float v = zt[j][tid]; r8[j] = __fmul_rn(v, v); }
#pragma unroll
        for (int i = 8; i < 64; i += 8)
#pragma unroll
            for (int j = 0; j < 8; ++j) {
                float v = zt[i + j][tid];
                r8[j] = __fadd_rn(r8[j], __fmul_rn(v, v));
            }
        float s01 = __fadd_rn(r8[0], r8[1]), s23 = __fadd_rn(r8[2], r8[3]);
        float s45 = __fadd_rn(r8[4], r8[5]), s67 = __fadd_rn(r8[6], r8[7]);
        zzsh[tid] = __fadd_rn(__fadd_rn(s01, s23), __fadd_rn(s45, s67));
    }

    const int ln = tid & 63, wv = tid >> 6;
    const int lr = ln & 15, lg = ln >> 4;

    short8v Ah[2][2], Al[2][2];
#pragma unroll
    for (int m = 0; m < 2; ++m)
#pragma unroll
        for (int s = 0; s < 2; ++s) {
            const int row = wv * 32 + m * 16 + lr;
            const int db = s * 32 + lg * 8;
#pragma unroll
            for (int j = 0; j < 8; ++j) {
                float f = zt[db + j][row];
                unsigned short hb = f2bf_rne(f);
                float hf = __uint_as_float((unsigned)hb << 16);
                unsigned short lb = f2bf_rne(f - hf);
                Ah[m][s][j] = (short)hb;
                Al[m][s][j] = (short)lb;
            }
        }
    __syncthreads();   // zt reads + zzsh writes done; smem free for e tiles

    float zzr[2][4];
#pragma unroll
    for (int m = 0; m < 2; ++m)
#pragma unroll
        for (int rg = 0; rg < 4; ++rg)
            zzr[m][rg] = zzsh[wv * 32 + m * 16 + lg * 4 + rg];

    float Zp[2][4], S1p[2][4], dmin[2][4];
    int imin[2][4];
#pragma unroll
    for (int m = 0; m < 2; ++m)
#pragma unroll
        for (int rg = 0; rg < 4; ++rg) {
            Zp[m][rg] = 0.f; S1p[m][rg] = 0.f; dmin[m][rg] = FLT_MAX; imin[m][rg] = 0;
        }

    for (int it = 0; it < 16; ++it) {
        const int kbase = ks * 2048 + it * 128;
        { // stage e tile (bf16 hi/lo, XOR-swizzled rows)
            const int r = tid >> 1, dh = tid & 1;
            const float* esrc = emb + (kbase + r) * 64 + dh * 32;
            float fv[32];
#pragma unroll
            for (int i = 0; i < 8; ++i) {
                float4 v = ((const float4*)esrc)[i];
                fv[4 * i] = v.x; fv[4 * i + 1] = v.y; fv[4 * i + 2] = v.z; fv[4 * i + 3] = v.w;
            }
            unsigned short hb[32], lb[32];
#pragma unroll
            for (int i = 0; i < 32; ++i) {
                hb[i] = f2bf_rne(fv[i]);
                float hf = __uint_as_float((unsigned)hb[i] << 16);
                lb[i] = f2bf_rne(fv[i] - hf);
            }
            const int sw = (r & 7) << 4;
#pragma unroll
            for (int c = 0; c < 4; ++c) {
                const int byt = (r * 128 + dh * 64 + c * 16) ^ sw;
                short8v hv, lv;
#pragma unroll
                for (int e = 0; e < 8; ++e) { hv[e] = (short)hb[c * 8 + e]; lv[e] = (short)lb[c * 8 + e]; }
                *(short8v*)((char*)ehb + byt) = hv;
                *(short8v*)((char*)elb + byt) = lv;
            }
            if (tid < 128) e2s[tid] = e2[kbase + tid];
        }
        __syncthreads();

        f32x4 acc[2][8];
#pragma unroll
        for (int m = 0; m < 2; ++m)
#pragma unroll
            for (int f = 0; f < 8; ++f) {
                f32x4 zz4 = {0.f, 0.f, 0.f, 0.f};
                acc[m][f] = zz4;
            }

#pragma unroll
        for (int f = 0; f < 8; ++f) {
            const int rr = f * 16 + lr;
            const int sw2 = (rr & 7) << 4;
            short8v Bh[2], Bl[2];
#pragma unroll
            for (int s = 0; s < 2; ++s) {
                const int byt = (rr * 128 + s * 64 + lg * 16) ^ sw2;
                Bh[s] = *(const short8v*)((const char*)ehb + byt);
                Bl[s] = *(const short8v*)((const char*)elb + byt);
            }
#pragma unroll
            for (int s = 0; s < 2; ++s)
#pragma unroll
                for (int m = 0; m < 2; ++m) {
                    acc[m][f] = __builtin_amdgcn_mfma_f32_16x16x32_bf16(Ah[m][s], Bh[s], acc[m][f], 0, 0, 0);
                    acc[m][f] = __builtin_amdgcn_mfma_f32_16x16x32_bf16(Ah[m][s], Bl[s], acc[m][f], 0, 0, 0);
                    acc[m][f] = __builtin_amdgcn_mfma_f32_16x16x32_bf16(Al[m][s], Bh[s], acc[m][f], 0, 0, 0);
                    acc[m][f] = __builtin_amdgcn_mfma_f32_16x16x32_bf16(Al[m][s], Bl[s], acc[m][f], 0, 0, 0);
                }
        }

#pragma unroll
        for (int f = 0; f < 8; ++f) {
            const float e2v = e2s[f * 16 + lr];
            const float c2 = e2v * C100L2E;
            const int kk = kbase + f * 16 + lr;
#pragma unroll
            for (int m = 0; m < 2; ++m)
#pragma unroll
                for (int rg = 0; rg < 4; ++rg) {
                    const float sdot = acc[m][f][rg];
                    const float t = fmaf(sdot, C200L2E, -c2);   // log2 exp(-100(ee-2s))
                    const float ex = __builtin_amdgcn_exp2f(t);
                    Zp[m][rg] += ex;
                    S1p[m][rg] = fmaf(t, ex, S1p[m][rg]);        // Sigma t*ex (mul ln2 later)
                    const float dnp = __fsub_rn(__fadd_rn(zzr[m][rg], e2v),
                                                __fmul_rn(2.f, sdot));
                    if (dnp < dmin[m][rg]) { dmin[m][rg] = dnp; imin[m][rg] = kk; }
                }
        }
        __syncthreads();
    }

    // reduce across the 16 lr lanes; lex tiebreak (min d, then min idx)
#pragma unroll
    for (int msk = 1; msk < 16; msk <<= 1) {
#pragma unroll
        for (int m = 0; m < 2; ++m)
#pragma unroll
            for (int rg = 0; rg < 4; ++rg) {
                float d2 = __shfl_xor(dmin[m][rg], msk, 16);
                int i2 = __shfl_xor(imin[m][rg], msk, 16);
                float Z2 = __shfl_xor(Zp[m][rg], msk, 16);
                float s2 = __shfl_xor(S1p[m][rg], msk, 16);
                if (d2 < dmin[m][rg] || (d2 == dmin[m][rg] && i2 < imin[m][rg])) {
                    dmin[m][rg] = d2; imin[m][rg] = i2;
                }
                Zp[m][rg] += Z2;
                S1p[m][rg] += s2;
            }
    }
    if (lr == 0) {
#pragma unroll
        for (int m = 0; m < 2; ++m)
#pragma unroll
            for (int rg = 0; rg < 4; ++rg) {
                const int n = n0 + wv * 32 + m * 16 + lg * 4 + rg;
                Zpart[ks * 16384 + n] = Zp[m][rg];
                S1part[ks * 16384 + n] = S1p[m][rg];
                dmpart[ks * 16384 + n] = dmin[m][rg];
                impart[ks * 16384 + n] = imin[m][rg];
            }
    }
}

__global__ __launch_bounds__(256) void k_rowred(
    const float* __restrict__ Zpart, const float* __restrict__ S1part,
    const float* __restrict__ dmpart, const int* __restrict__ impart,
    float* __restrict__ invZ, int* __restrict__ minidx,
    float* __restrict__ out_idx, double* __restrict__ pse_sum)
{
    const int n = blockIdx.x * 256 + threadIdx.x;
    float Z = __fadd_rn(__fadd_rn(Zpart[n], Zpart[16384 + n]),
                        __fadd_rn(Zpart[32768 + n], Zpart[49152 + n]));
    float S1 = __fadd_rn(__fadd_rn(S1part[n], S1part[16384 + n]),
                         __fadd_rn(S1part[32768 + n], S1part[49152 + n]));
    float dm = dmpart[n];
    int im = impart[n];
#pragma unroll
    for (int ksp = 1; ksp < 4; ++ksp) {
        float d2 = dmpart[ksp * 16384 + n];
        int i2 = impart[ksp * 16384 + n];
        if (d2 < dm || (d2 == dm && i2 < im)) { dm = d2; im = i2; }
    }
    minidx[n] = im;
    out_idx[n] = (float)im;
    float iz = 1.0f / Z;
    invZ[n] = iz;
    double h = log((double)Z) - LN2 * (double)S1 * (double)iz;
#pragma unroll
    for (int m = 32; m > 0; m >>= 1) h += __shfl_xor(h, m, 64);
    if ((threadIdx.x & 63) == 0) atomicAdd(pse_sum, h);
}

// ---- pass 2: avg_prob accumulation ----
__global__ __launch_bounds__(256) void k_pass2(
    const float* __restrict__ z, const float* __restrict__ emb,
    const float* __restrict__ e2, const float* __restrict__ invZ,
    float* __restrict__ avg_acc)
{
    __shared__ __align__(16) char smem[34816];
    float (*zt)[136] = (float (*)[136])smem;
    short* ehb = (short*)smem;
    short* elb = (short*)(smem + 16384);
    float* e2s = (float*)(smem + 32768);

    const int tid = threadIdx.x;
    const int panel = blockIdx.x >> 2;
    const int ks = blockIdx.x & 3;
    const int n0 = panel * 128;

    {
        const int c = tid >> 2, q = tid & 3;
        const float* src = z + ((n0 >> 10) * 64 + c) * 1024 + (n0 & 1023) + q * 32;
#pragma unroll
        for (int i = 0; i < 8; ++i) {
            float4 v = ((const float4*)src)[i];
            *(float4*)&zt[c][q * 32 + 4 * i] = v;
        }
    }
    __syncthreads();

    const int ln = tid & 63, wv = tid >> 6;
    const int lr = ln & 15, lg = ln >> 4;

    short8v Ah[2][2], Al[2][2];
#pragma unroll
    for (int m = 0; m < 2; ++m)
#pragma unroll
        for (int s = 0; s < 2; ++s) {
            const int row = wv * 32 + m * 16 + lr;
            const int db = s * 32 + lg * 8;
#pragma unroll
            for (int j = 0; j < 8; ++j) {
                float f = zt[db + j][row];
                unsigned short hb = f2bf_rne(f);
                float hf = __uint_as_float((unsigned)hb << 16);
                unsigned short lb = f2bf_rne(f - hf);
                Ah[m][s][j] = (short)hb;
                Al[m][s][j] = (short)lb;
            }
        }
    __syncthreads();

    float izr[2][4];
#pragma unroll
    for (int m = 0; m < 2; ++m)
#pragma unroll
        for (int rg = 0; rg < 4; ++rg)
            izr[m][rg] = invZ[n0 + wv * 32 + m * 16 + lg * 4 + rg];

    for (int it = 0; it < 16; ++it) {
        const int kbase = ks * 2048 + it * 128;
        {
            const int r = tid >> 1, dh = tid & 1;
            const float* esrc = emb + (kbase + r) * 64 + dh * 32;
            float fv[32];
#pragma unroll
            for (int i = 0; i < 8; ++i) {
                float4 v = ((const float4*)esrc)[i];
                fv[4 * i] = v.x; fv[4 * i + 1] = v.y; fv[4 * i + 2] = v.z; fv[4 * i + 3] = v.w;
            }
            unsigned short hb[32], lb[32];
#pragma unroll
            for (int i = 0; i < 32; ++i) {
                hb[i] = f2bf_rne(fv[i]);
                float hf = __uint_as_float((unsigned)hb[i] << 16);
                lb[i] = f2bf_rne(fv[i] - hf);
            }
            const int sw = (r & 7) << 4;
#pragma unroll
            for (int c = 0; c < 4; ++c) {
                const int byt = (r * 128 + dh * 64 + c * 16) ^ sw;
                short8v hv, lv;
#pragma unroll
                for (int e = 0; e < 8; ++e) { hv[e] = (short)hb[c * 8 + e]; lv[e] = (short)lb[c * 8 + e]; }
                *(short8v*)((char*)ehb + byt) = hv;
                *(short8v*)((char*)elb + byt) = lv;
            }
            if (tid < 128) e2s[tid] = e2[kbase + tid];
        }
        __syncthreads();

        f32x4 acc[2][8];
#pragma unroll
        for (int m = 0; m < 2; ++m)
#pragma unroll
            for (int f = 0; f < 8; ++f) {
                f32x4 zz4 = {0.f, 0.f, 0.f, 0.f};
                acc[m][f] = zz4;
            }

#pragma unroll
        for (int f = 0; f < 8; ++f) {
            const int rr = f * 16 + lr;
            const int sw2 = (rr & 7) << 4;
            short8v Bh[2], Bl[2];
#pragma unroll
            for (int s = 0; s < 2; ++s) {
                const int byt = (rr * 128 + s * 64 + lg * 16) ^ sw2;
                Bh[s] = *(const short8v*)((const char*)ehb + byt);
                Bl[s] = *(const short8v*)((const char*)elb + byt);
            }
#pragma unroll
            for (int s = 0; s < 2; ++s)
#pragma unroll
                for (int m = 0; m < 2; ++m) {
                    acc[m][f] = __builtin_amdgcn_mfma_f32_16x16x32_bf16(Ah[m][s], Bh[s], acc[m][f], 0, 0, 0);
                    acc[m][f] = __builtin_amdgcn_mfma_f32_16x16x32_bf16(Ah[m][s], Bl[s], acc[m][f], 0, 0, 0);
                    acc[m][f] = __builtin_amdgcn_mfma_f32_16x16x32_bf16(Al[m][s], Bh[s], acc[m][f], 0, 0, 0);
                    acc[m][f] = __builtin_amdgcn_mfma_f32_16x16x32_bf16(Al[m][s], Bl[s], acc[m][f], 0, 0, 0);
                }
        }

#pragma unroll
        for (int f = 0; f < 8; ++f) {
            const float c2 = e2s[f * 16 + lr] * C100L2E;
            float cs = 0.f;
#pragma unroll
            for (int m = 0; m < 2; ++m)
#pragma unroll
                for (int rg = 0; rg < 4; ++rg) {
                    const float t = fmaf(acc[m][f][rg], C200L2E, -c2);
                    const float ex = __builtin_amdgcn_exp2f(t);
                    cs = fmaf(ex, izr[m][rg], cs);
                }
            cs += __shfl_xor(cs, 16, 64);
            cs += __shfl_xor(cs, 32, 64);
            if (lg == 0) atomicAdd(&avg_acc[kbase + f * 16 + lr], cs);
        }
        __syncthreads();
    }
}

// gather quantized output + per-block loss partial (no contended atomics)
__global__ __launch_bounds__(256) void k_quant(
    const float* __restrict__ z, const float* __restrict__ emb,
    const int* __restrict__ minidx, float* __restrict__ out,
    double* __restrict__ loss_part)
{
    __shared__ float lred[4];
    const int o = blockIdx.x * 256 + threadIdx.x;
    const int n = ((o >> 16) << 10) + (o & 1023);
    const int c = (o >> 10) & 63;
    const int idx = minidx[n];
    const float e = emb[idx * 64 + c];
    const float zv = z[o];
    out[o] = e;
    float d = e - zv;
    float sq = d * d;
#pragma unroll
    for (int m = 32; m > 0; m >>= 1) sq += __shfl_xor(sq, m, 64);
    if ((threadIdx.x & 63) == 0) lred[threadIdx.x >> 6] = sq;
    __syncthreads();
    if (threadIdx.x == 0)
        loss_part[blockIdx.x] = (double)lred[0] + (double)lred[1]
                              + (double)lred[2] + (double)lred[3];
}

__global__ __launch_bounds__(256) void k_final(
    const float* __restrict__ avg_acc, const double* __restrict__ pse_sum,
    const double* __restrict__ loss_part, float* __restrict__ out)
{
    __shared__ double red[256];
    const int tid = threadIdx.x;

    // loss: sum 4096 per-block partials
    double lsum = 0.0;
    for (int k = tid; k < 4096; k += 256) lsum += loss_part[k];
    red[tid] = lsum;
    __syncthreads();
    for (int s = 128; s > 0; s >>= 1) {
        if (tid < s) red[tid] += red[tid + s];
        __syncthreads();
    }
    double ltot = red[0];
    __syncthreads();

    // codebook entropy
    double local = 0.0;
    for (int k = tid; k < 8192; k += 256) {
        float p = avg_acc[k] * (1.0f / 16384.0f);
        float cl = fmaxf(p, 1e-5f);
        local += (double)(-p * logf(cl));
    }
    red[tid] = local;
    __syncthreads();
    for (int s = 128; s > 0; s >>= 1) {
        if (tid < s) red[tid] += red[tid + s];
        __syncthreads();
    }
    if (tid == 0) {
        double ce = red[0];
        double pse = pse_sum[0] / 16384.0;
        out[1048576] = (float)(1.25 * ltot / 1048576.0);
        out[1048577] = (float)(pse - ce);
    }
}

extern "C" void kernel_launch(void* const* d_in, const int* in_sizes, int n_in,
                              void* d_out, int out_size, void* d_ws, size_t ws_size,
                              hipStream_t stream) {
    const float* z = (const float*)d_in[0];
    const float* emb = (const float*)d_in[1];
    float* out = (float*)d_out;
    char* ws = (char*)d_ws;
    float* e2 = (float*)(ws);
    float* invZ = (float*)(ws + 32768);
    int* minidx = (int*)(ws + 98304);
    float* avg_acc = (float*)(ws + 163840);
    double* pse_sum = (double*)(ws + 196608);
    float* Zpart = (float*)(ws + 196624);
    float* S1part = (float*)(ws + 196624 + 262144);
    float* dmpart = (float*)(ws + 196624 + 524288);
    int* impart = (int*)(ws + 196624 + 786432);
    double* loss_part = (double*)(ws + 1245200);

    hipMemsetAsync(ws + 163840, 0, 32768 + 16, stream);

    k_e2<<<32, 256, 0, stream>>>(emb, e2);
    k_pass1<<<512, 256, 0, stream>>>(z, emb, e2, Zpart, S1part, dmpart, impart);
    k_rowred<<<64, 256, 0, stream>>>(Zpart, S1part, dmpart, impart,
                                     invZ, minidx, out + 1048578, pse_sum);
    k_pass2<<<512, 256, 0, stream>>>(z, emb, e2, invZ, avg_acc);
    k_quant<<<4096, 256, 0, stream>>>(z, emb, minidx, out, loss_part);
    k_final<<<1, 256, 0, stream>>>(avg_acc, pse_sum, loss_part, out);
}

// Round 5
// 226.278 us; speedup vs baseline: 4.1524x; 1.0698x over previous
//
#include <hip/hip_runtime.h>
#include <cfloat>

// z:   [16, 64, 32, 32] f32 -> N = 16384 rows of dim 64 (row n = b*1024 + hw)
// emb: [8192, 64] f32
// out (f32): quantized [1048576] | loss [1] | entropy_aux [1] | min_indices [16384]
//
// s = z.e via 4-term bf16-split MFMA (zh+zl)(eh+el), f32 accumulate.
// argmin on numpy-rounding-emulated d = fl(fl(zz+ee) - fl(2s)); 2s is exact.

typedef __attribute__((ext_vector_type(8))) short short8v;   // 8 bf16
typedef __attribute__((ext_vector_type(4))) float f32x4;

#define C100L2E 144.26950408889634f   // 100*log2(e)
#define C200L2E 288.53900817779268f   // 200*log2(e)
#define LN2 0.6931471805599453

// ws layout (bytes):
#define BLOB_TILE 33792               // 16K hi bf16 + 16K lo bf16 + 512B e2 (+pad)
#define OFF_BLOB   0                  // 64 tiles * 33792 = 2162688
#define OFF_INVZ   2162688            // f32[16384]
#define OFF_MINIDX 2228224            // i32[16384]
#define OFF_AVG    2293760            // f32[8192]   (zeroed each launch)
#define OFF_PSE    2326528            // double      (zeroed each launch)
#define OFF_ZPART  2326544            // f32[4][16384]
#define OFF_S1PART (OFF_ZPART + 262144)
#define OFF_DMPART (OFF_S1PART + 262144)
#define OFF_IMPART (OFF_DMPART + 262144)
#define OFF_LOSSP  (OFF_IMPART + 262144)  // dbl[4096] fully rewritten each launch

__device__ __forceinline__ unsigned short f2bf_rne(float f) {
    unsigned u = __float_as_uint(f);
    u = (u + 0x7fffu + ((u >> 16) & 1u)) >> 16;
    return (unsigned short)u;
}

__device__ __forceinline__ void gload_lds16(const void* g, void* l) {
    __builtin_amdgcn_global_load_lds(
        (const __attribute__((address_space(1))) unsigned int*)g,
        (__attribute__((address_space(3))) unsigned int*)l, 16, 0, 0);
}

// Build pre-swizzled bf16 hi/lo tile images + per-tile e2 (numpy pairwise-8).
__global__ __launch_bounds__(256) void k_prep(const float* __restrict__ emb,
                                              char* __restrict__ blob) {
    const int k = blockIdx.x * 256 + threadIdx.x;   // 8192 rows
    const float* row = emb + k * 64;
    float fv[64];
#pragma unroll
    for (int i = 0; i < 16; ++i) {
        float4 v = ((const float4*)row)[i];
        fv[4 * i] = v.x; fv[4 * i + 1] = v.y; fv[4 * i + 2] = v.z; fv[4 * i + 3] = v.w;
    }
    // e2 numpy pairwise-8
    float r8[8];
#pragma unroll
    for (int j = 0; j < 8; ++j) r8[j] = __fmul_rn(fv[j], fv[j]);
#pragma unroll
    for (int i = 8; i < 64; i += 8)
#pragma unroll
        for (int j = 0; j < 8; ++j)
            r8[j] = __fadd_rn(r8[j], __fmul_rn(fv[i + j], fv[i + j]));
    float s01 = __fadd_rn(r8[0], r8[1]), s23 = __fadd_rn(r8[2], r8[3]);
    float s45 = __fadd_rn(r8[4], r8[5]), s67 = __fadd_rn(r8[6], r8[7]);
    float e2 = __fadd_rn(__fadd_rn(s01, s23), __fadd_rn(s45, s67));

    char* tb = blob + (size_t)(k >> 7) * BLOB_TILE;
    const int r = k & 127;
    ((float*)(tb + 32768))[r] = e2;
    const int sw = (r & 7) << 4;
#pragma unroll
    for (int dh = 0; dh < 2; ++dh)
#pragma unroll
        for (int cg = 0; cg < 4; ++cg) {
            short8v hv, lv;
#pragma unroll
            for (int e = 0; e < 8; ++e) {
                float f = fv[dh * 32 + cg * 8 + e];
                unsigned short hb = f2bf_rne(f);
                float hf = __uint_as_float((unsigned)hb << 16);
                hv[e] = (short)hb;
                lv[e] = (short)f2bf_rne(f - hf);
            }
            const int byt = (r * 128 + dh * 64 + cg * 16) ^ sw;
            *(short8v*)(tb + byt) = hv;
            *(short8v*)(tb + 16384 + byt) = lv;
        }
}

// stage one 33KB tile image into LDS via global_load_lds (linear, wave-uniform base)
#define STAGE(TILE)                                                              \
    {                                                                            \
        const char* gsrc = blob + (size_t)(TILE) * BLOB_TILE;                    \
        char* ldst = smem + ((tid >> 6) << 10);                                  \
        const char* g = gsrc + tid * 16;                                         \
        _Pragma("unroll")                                                        \
        for (int q = 0; q < 8; ++q)                                              \
            gload_lds16(g + q * 4096, ldst + q * 4096);                          \
        if (tid < 32) gload_lds16(gsrc + 32768 + tid * 16, smem + 32768);        \
    }

// ---- pass 1: per-row stats (argmin, Z, S1') over a 2048-wide k split ----
__global__ __launch_bounds__(256) void k_pass1(
    const float* __restrict__ z, const char* __restrict__ blob,
    float* __restrict__ Zpart, float* __restrict__ S1part,
    float* __restrict__ dmpart, int* __restrict__ impart)
{
    __shared__ __align__(16) char smem[BLOB_TILE];
    __shared__ float zzsh[64];
    float (*zt)[68] = (float (*)[68])smem;   // phase A: z staging, d-major (17408B)

    const int tid = threadIdx.x;
    const int panel = blockIdx.x >> 2;
    const int ks = blockIdx.x & 3;
    const int n0 = panel * 64;

    { // stage z panel (64 rows): zt[d][r]
        const int c = tid & 63, rq = (tid >> 6) * 16;
        const float* src = z + ((n0 >> 10) * 64 + c) * 1024 + (n0 & 1023) + rq;
#pragma unroll
        for (int i = 0; i < 4; ++i) {
            float4 v = ((const float4*)src)[i];
            *(float4*)&zt[c][rq + 4 * i] = v;
        }
    }
    __syncthreads();
    if (tid < 64) { // numpy pairwise-8 ||z||^2
        float r8[8];
#pragma unroll
        for (int j = 0; j < 8; ++j) { float v = zt[j][tid]; r8[j] = __fmul_rn(v, v); }
#pragma unroll
        for (int i = 8; i < 64; i += 8)
#pragma unroll
            for (int j = 0; j < 8; ++j) {
                float v = zt[i + j][tid];
                r8[j] = __fadd_rn(r8[j], __fmul_rn(v, v));
            }
        float s01 = __fadd_rn(r8[0], r8[1]), s23 = __fadd_rn(r8[2], r8[3]);
        float s45 = __fadd_rn(r8[4], r8[5]), s67 = __fadd_rn(r8[6], r8[7]);
        zzsh[tid] = __fadd_rn(__fadd_rn(s01, s23), __fadd_rn(s45, s67));
    }

    const int ln = tid & 63, wv = tid >> 6;
    const int lr = ln & 15, lg = ln >> 4;

    // A-frags in registers: row wv*16+lr, k = s*32 + lg*8 + j
    short8v Ah[2], Al[2];
#pragma unroll
    for (int s = 0; s < 2; ++s) {
        const int row = wv * 16 + lr;
        const int db = s * 32 + lg * 8;
#pragma unroll
        for (int j = 0; j < 8; ++j) {
            float f = zt[db + j][row];
            unsigned short hb = f2bf_rne(f);
            float hf = __uint_as_float((unsigned)hb << 16);
            Ah[s][j] = (short)hb;
            Al[s][j] = (short)f2bf_rne(f - hf);
        }
    }
    __syncthreads();   // zt reads done; smem free for tile images

    float zzr[4];
#pragma unroll
    for (int rg = 0; rg < 4; ++rg) zzr[rg] = zzsh[wv * 16 + lg * 4 + rg];

    STAGE(ks * 16);    // prefetch first tile

    float Zp[4] = {0.f, 0.f, 0.f, 0.f}, S1p[4] = {0.f, 0.f, 0.f, 0.f};
    float dmin[4] = {FLT_MAX, FLT_MAX, FLT_MAX, FLT_MAX};
    int imin[4] = {0, 0, 0, 0};

    for (int it = 0; it < 16; ++it) {
        const int kbase = ks * 2048 + it * 128;
        __syncthreads();   // drains vmcnt (tile landed) + barrier

        f32x4 acc[8];
#pragma unroll
        for (int f = 0; f < 8; ++f) { f32x4 zv = {0.f, 0.f, 0.f, 0.f}; acc[f] = zv; }

#pragma unroll
        for (int f = 0; f < 8; ++f) {
            const int rr = f * 16 + lr;
            const int sw2 = (rr & 7) << 4;
            short8v Bh[2], Bl[2];
#pragma unroll
            for (int s = 0; s < 2; ++s) {
                const int byt = (rr * 128 + s * 64 + lg * 16) ^ sw2;
                Bh[s] = *(const short8v*)(smem + byt);
                Bl[s] = *(const short8v*)(smem + 16384 + byt);
            }
#pragma unroll
            for (int s = 0; s < 2; ++s) {
                acc[f] = __builtin_amdgcn_mfma_f32_16x16x32_bf16(Ah[s], Bh[s], acc[f], 0, 0, 0);
                acc[f] = __builtin_amdgcn_mfma_f32_16x16x32_bf16(Ah[s], Bl[s], acc[f], 0, 0, 0);
                acc[f] = __builtin_amdgcn_mfma_f32_16x16x32_bf16(Al[s], Bh[s], acc[f], 0, 0, 0);
                acc[f] = __builtin_amdgcn_mfma_f32_16x16x32_bf16(Al[s], Bl[s], acc[f], 0, 0, 0);
            }
        }

        float e2v[8];
#pragma unroll
        for (int f = 0; f < 8; ++f)
            e2v[f] = *(const float*)(smem + 32768 + (f * 16 + lr) * 4);

        __syncthreads();               // all waves done reading this tile
        if (it < 15) STAGE(ks * 16 + it + 1);   // prefetch next under epilogue

#pragma unroll
        for (int f = 0; f < 8; ++f) {
            const float c2 = e2v[f] * C100L2E;
            const int kk = kbase + f * 16 + lr;
#pragma unroll
            for (int rg = 0; rg < 4; ++rg) {
                const float sdot = acc[f][rg];
                const float t = fmaf(sdot, C200L2E, -c2);
                const float ex = __builtin_amdgcn_exp2f(t);
                Zp[rg] += ex;
                S1p[rg] = fmaf(t, ex, S1p[rg]);
                const float dnp = __fsub_rn(__fadd_rn(zzr[rg], e2v[f]),
                                            __fmul_rn(2.f, sdot));
                if (dnp < dmin[rg]) { dmin[rg] = dnp; imin[rg] = kk; }
            }
        }
    }

    // reduce across the 16 lr lanes; lex tiebreak (min d, then min idx)
#pragma unroll
    for (int msk = 1; msk < 16; msk <<= 1) {
#pragma unroll
        for (int rg = 0; rg < 4; ++rg) {
            float d2 = __shfl_xor(dmin[rg], msk, 16);
            int i2 = __shfl_xor(imin[rg], msk, 16);
            float Z2 = __shfl_xor(Zp[rg], msk, 16);
            float s2 = __shfl_xor(S1p[rg], msk, 16);
            if (d2 < dmin[rg] || (d2 == dmin[rg] && i2 < imin[rg])) {
                dmin[rg] = d2; imin[rg] = i2;
            }
            Zp[rg] += Z2;
            S1p[rg] += s2;
        }
    }
    if (lr == 0) {
#pragma unroll
        for (int rg = 0; rg < 4; ++rg) {
            const int n = n0 + wv * 16 + lg * 4 + rg;
            Zpart[ks * 16384 + n] = Zp[rg];
            S1part[ks * 16384 + n] = S1p[rg];
            dmpart[ks * 16384 + n] = dmin[rg];
            impart[ks * 16384 + n] = imin[rg];
        }
    }
}

__global__ __launch_bounds__(256) void k_rowred(
    const float* __restrict__ Zpart, const float* __restrict__ S1part,
    const float* __restrict__ dmpart, const int* __restrict__ impart,
    float* __restrict__ invZ, int* __restrict__ minidx,
    float* __restrict__ out_idx, double* __restrict__ pse_sum)
{
    const int n = blockIdx.x * 256 + threadIdx.x;
    float Z = __fadd_rn(__fadd_rn(Zpart[n], Zpart[16384 + n]),
                        __fadd_rn(Zpart[32768 + n], Zpart[49152 + n]));
    float S1 = __fadd_rn(__fadd_rn(S1part[n], S1part[16384 + n]),
                         __fadd_rn(S1part[32768 + n], S1part[49152 + n]));
    float dm = dmpart[n];
    int im = impart[n];
#pragma unroll
    for (int ksp = 1; ksp < 4; ++ksp) {
        float d2 = dmpart[ksp * 16384 + n];
        int i2 = impart[ksp * 16384 + n];
        if (d2 < dm || (d2 == dm && i2 < im)) { dm = d2; im = i2; }
    }
    minidx[n] = im;
    out_idx[n] = (float)im;
    float iz = 1.0f / Z;
    invZ[n] = iz;
    double h = log((double)Z) - LN2 * (double)S1 * (double)iz;
#pragma unroll
    for (int m = 32; m > 0; m >>= 1) h += __shfl_xor(h, m, 64);
    if ((threadIdx.x & 63) == 0) atomicAdd(pse_sum, h);
}

// ---- pass 2: avg_prob accumulation ----
__global__ __launch_bounds__(256) void k_pass2(
    const float* __restrict__ z, const char* __restrict__ blob,
    const float* __restrict__ invZ, float* __restrict__ avg_acc)
{
    __shared__ __align__(16) char smem[BLOB_TILE];
    float (*zt)[68] = (float (*)[68])smem;

    const int tid = threadIdx.x;
    const int panel = blockIdx.x >> 2;
    const int ks = blockIdx.x & 3;
    const int n0 = panel * 64;

    {
        const int c = tid & 63, rq = (tid >> 6) * 16;
        const float* src = z + ((n0 >> 10) * 64 + c) * 1024 + (n0 & 1023) + rq;
#pragma unroll
        for (int i = 0; i < 4; ++i) {
            float4 v = ((const float4*)src)[i];
            *(float4*)&zt[c][rq + 4 * i] = v;
        }
    }
    __syncthreads();

    const int ln = tid & 63, wv = tid >> 6;
    const int lr = ln & 15, lg = ln >> 4;

    short8v Ah[2], Al[2];
#pragma unroll
    for (int s = 0; s < 2; ++s) {
        const int row = wv * 16 + lr;
        const int db = s * 32 + lg * 8;
#pragma unroll
        for (int j = 0; j < 8; ++j) {
            float f = zt[db + j][row];
            unsigned short hb = f2bf_rne(f);
            float hf = __uint_as_float((unsigned)hb << 16);
            Ah[s][j] = (short)hb;
            Al[s][j] = (short)f2bf_rne(f - hf);
        }
    }
    __syncthreads();

    float izr[4];
#pragma unroll
    for (int rg = 0; rg < 4; ++rg)
        izr[rg] = invZ[n0 + wv * 16 + lg * 4 + rg];

    STAGE(ks * 16);

    for (int it = 0; it < 16; ++it) {
        const int kbase = ks * 2048 + it * 128;
        __syncthreads();

        f32x4 acc[8];
#pragma unroll
        for (int f = 0; f < 8; ++f) { f32x4 zv = {0.f, 0.f, 0.f, 0.f}; acc[f] = zv; }

#pragma unroll
        for (int f = 0; f < 8; ++f) {
            const int rr = f * 16 + lr;
            const int sw2 = (rr & 7) << 4;
            short8v Bh[2], Bl[2];
#pragma unroll
            for (int s = 0; s < 2; ++s) {
                const int byt = (rr * 128 + s * 64 + lg * 16) ^ sw2;
                Bh[s] = *(const short8v*)(smem + byt);
                Bl[s] = *(const short8v*)(smem + 16384 + byt);
            }
#pragma unroll
            for (int s = 0; s < 2; ++s) {
                acc[f] = __builtin_amdgcn_mfma_f32_16x16x32_bf16(Ah[s], Bh[s], acc[f], 0, 0, 0);
                acc[f] = __builtin_amdgcn_mfma_f32_16x16x32_bf16(Ah[s], Bl[s], acc[f], 0, 0, 0);
                acc[f] = __builtin_amdgcn_mfma_f32_16x16x32_bf16(Al[s], Bh[s], acc[f], 0, 0, 0);
                acc[f] = __builtin_amdgcn_mfma_f32_16x16x32_bf16(Al[s], Bl[s], acc[f], 0, 0, 0);
            }
        }

        float e2v[8];
#pragma unroll
        for (int f = 0; f < 8; ++f)
            e2v[f] = *(const float*)(smem + 32768 + (f * 16 + lr) * 4);

        __syncthreads();
        if (it < 15) STAGE(ks * 16 + it + 1);

#pragma unroll
        for (int f = 0; f < 8; ++f) {
            const float c2 = e2v[f] * C100L2E;
            float cs = 0.f;
#pragma unroll
            for (int rg = 0; rg < 4; ++rg) {
                const float t = fmaf(acc[f][rg], C200L2E, -c2);
                const float ex = __builtin_amdgcn_exp2f(t);
                cs = fmaf(ex, izr[rg], cs);
            }
            cs += __shfl_xor(cs, 16, 64);
            cs += __shfl_xor(cs, 32, 64);
            if (lg == 0) atomicAdd(&avg_acc[kbase + f * 16 + lr], cs);
        }
    }
}

// gather quantized output + per-block loss partial (no contended atomics)
__global__ __launch_bounds__(256) void k_quant(
    const float* __restrict__ z, const float* __restrict__ emb,
    const int* __restrict__ minidx, float* __restrict__ out,
    double* __restrict__ loss_part)
{
    __shared__ float lred[4];
    const int o = blockIdx.x * 256 + threadIdx.x;
    const int n = ((o >> 16) << 10) + (o & 1023);
    const int c = (o >> 10) & 63;
    const int idx = minidx[n];
    const float e = emb[idx * 64 + c];
    const float zv = z[o];
    out[o] = e;
    float d = e - zv;
    float sq = d * d;
#pragma unroll
    for (int m = 32; m > 0; m >>= 1) sq += __shfl_xor(sq, m, 64);
    if ((threadIdx.x & 63) == 0) lred[threadIdx.x >> 6] = sq;
    __syncthreads();
    if (threadIdx.x == 0)
        loss_part[blockIdx.x] = (double)lred[0] + (double)lred[1]
                              + (double)lred[2] + (double)lred[3];
}

__global__ __launch_bounds__(256) void k_final(
    const float* __restrict__ avg_acc, const double* __restrict__ pse_sum,
    const double* __restrict__ loss_part, float* __restrict__ out)
{
    __shared__ double red[256];
    const int tid = threadIdx.x;

    double lsum = 0.0;
    for (int k = tid; k < 4096; k += 256) lsum += loss_part[k];
    red[tid] = lsum;
    __syncthreads();
    for (int s = 128; s > 0; s >>= 1) {
        if (tid < s) red[tid] += red[tid + s];
        __syncthreads();
    }
    double ltot = red[0];
    __syncthreads();

    double local = 0.0;
    for (int k = tid; k < 8192; k += 256) {
        float p = avg_acc[k] * (1.0f / 16384.0f);
        float cl = fmaxf(p, 1e-5f);
        local += (double)(-p * logf(cl));
    }
    red[tid] = local;
    __syncthreads();
    for (int s = 128; s > 0; s >>= 1) {
        if (tid < s) red[tid] += red[tid + s];
        __syncthreads();
    }
    if (tid == 0) {
        double ce = red[0];
        double pse = pse_sum[0] / 16384.0;
        out[1048576] = (float)(1.25 * ltot / 1048576.0);
        out[1048577] = (float)(pse - ce);
    }
}

extern "C" void kernel_launch(void* const* d_in, const int* in_sizes, int n_in,
                              void* d_out, int out_size, void* d_ws, size_t ws_size,
                              hipStream_t stream) {
    const float* z = (const float*)d_in[0];
    const float* emb = (const float*)d_in[1];
    float* out = (float*)d_out;
    char* ws = (char*)d_ws;
    char* blob = ws + OFF_BLOB;
    float* invZ = (float*)(ws + OFF_INVZ);
    int* minidx = (int*)(ws + OFF_MINIDX);
    float* avg_acc = (float*)(ws + OFF_AVG);
    double* pse_sum = (double*)(ws + OFF_PSE);
    float* Zpart = (float*)(ws + OFF_ZPART);
    float* S1part = (float*)(ws + OFF_S1PART);
    float* dmpart = (float*)(ws + OFF_DMPART);
    int* impart = (int*)(ws + OFF_IMPART);
    double* loss_part = (double*)(ws + OFF_LOSSP);

    // zero avg_acc + pse_sum every launch (no cross-replay state)
    hipMemsetAsync(ws + OFF_AVG, 0, 32768 + 16, stream);

    k_prep<<<32, 256, 0, stream>>>(emb, blob);
    k_pass1<<<1024, 256, 0, stream>>>(z, blob, Zpart, S1part, dmpart, impart);
    k_rowred<<<64, 256, 0, stream>>>(Zpart, S1part, dmpart, impart,
                                     invZ, minidx, out + 1048578, pse_sum);
    k_pass2<<<1024, 256, 0, stream>>>(z, blob, invZ, avg_acc);
    k_quant<<<4096, 256, 0, stream>>>(z, emb, minidx, out, loss_part);
    k_final<<<1, 256, 0, stream>>>(avg_acc, pse_sum, loss_part, out);
}

// Round 6
// 198.659 us; speedup vs baseline: 4.7297x; 1.1390x over previous
//
#include <hip/hip_runtime.h>
#include <cfloat>

// z:   [16, 64, 32, 32] f32 -> N = 16384 rows of dim 64 (row n = b*1024 + hw)
// emb: [8192, 64] f32
// out (f32): quantized [1048576] | loss [1] | entropy_aux [1] | min_indices [16384]
//
// s = z.e via 4-term bf16-split MFMA (zh+zl)(eh+el), f32 accumulate.
// argmin on numpy-rounding-emulated d = fl(fl(zz+ee) - fl(2s)); 2s is exact.

typedef __attribute__((ext_vector_type(8))) short short8v;   // 8 bf16
typedef __attribute__((ext_vector_type(4))) float f32x4;

#define C100L2E 144.26950408889634f   // 100*log2(e)
#define C200L2E 288.53900817779268f   // 200*log2(e)
#define LN2 0.6931471805599453

// ws layout (bytes):
#define BLOB_TILE 33792               // 16K hi bf16 + 16K lo bf16 + 512B e2 (+pad)
#define OFF_BLOB   0                  // 64 tiles * 33792 = 2162688
#define OFF_INVZ   2162688            // f32[16384]
#define OFF_MINIDX 2228224            // i32[16384]
#define OFF_AVG    2293760            // f32[8192]   (zeroed each launch)
#define OFF_PSE    2326528            // double      (zeroed each launch)
#define OFF_ZPART  2326544            // f32[4][16384]
#define OFF_S1PART (OFF_ZPART + 262144)
#define OFF_DMPART (OFF_S1PART + 262144)
#define OFF_IMPART (OFF_DMPART + 262144)
#define OFF_LOSSP  (OFF_IMPART + 262144)  // dbl[4096] fully rewritten each launch

__device__ __forceinline__ unsigned short f2bf_rne(float f) {
    unsigned u = __float_as_uint(f);
    u = (u + 0x7fffu + ((u >> 16) & 1u)) >> 16;
    return (unsigned short)u;
}

__device__ __forceinline__ void gload_lds16(const void* g, void* l) {
    __builtin_amdgcn_global_load_lds(
        (const __attribute__((address_space(1))) unsigned int*)g,
        (__attribute__((address_space(3))) unsigned int*)l, 16, 0, 0);
}

// Build pre-swizzled bf16 hi/lo tile images + per-tile e2 (numpy pairwise-8).
__global__ __launch_bounds__(256) void k_prep(const float* __restrict__ emb,
                                              char* __restrict__ blob) {
    const int k = blockIdx.x * 256 + threadIdx.x;   // 8192 rows
    const float* row = emb + k * 64;
    float fv[64];
#pragma unroll
    for (int i = 0; i < 16; ++i) {
        float4 v = ((const float4*)row)[i];
        fv[4 * i] = v.x; fv[4 * i + 1] = v.y; fv[4 * i + 2] = v.z; fv[4 * i + 3] = v.w;
    }
    float r8[8];
#pragma unroll
    for (int j = 0; j < 8; ++j) r8[j] = __fmul_rn(fv[j], fv[j]);
#pragma unroll
    for (int i = 8; i < 64; i += 8)
#pragma unroll
        for (int j = 0; j < 8; ++j)
            r8[j] = __fadd_rn(r8[j], __fmul_rn(fv[i + j], fv[i + j]));
    float s01 = __fadd_rn(r8[0], r8[1]), s23 = __fadd_rn(r8[2], r8[3]);
    float s45 = __fadd_rn(r8[4], r8[5]), s67 = __fadd_rn(r8[6], r8[7]);
    float e2 = __fadd_rn(__fadd_rn(s01, s23), __fadd_rn(s45, s67));

    char* tb = blob + (size_t)(k >> 7) * BLOB_TILE;
    const int r = k & 127;
    ((float*)(tb + 32768))[r] = e2;
    const int sw = (r & 7) << 4;
#pragma unroll
    for (int dh = 0; dh < 2; ++dh)
#pragma unroll
        for (int cg = 0; cg < 4; ++cg) {
            short8v hv, lv;
#pragma unroll
            for (int e = 0; e < 8; ++e) {
                float f = fv[dh * 32 + cg * 8 + e];
                unsigned short hb = f2bf_rne(f);
                float hf = __uint_as_float((unsigned)hb << 16);
                hv[e] = (short)hb;
                lv[e] = (short)f2bf_rne(f - hf);
            }
            const int byt = (r * 128 + dh * 64 + cg * 16) ^ sw;
            *(short8v*)(tb + byt) = hv;
            *(short8v*)(tb + 16384 + byt) = lv;
        }
}

// stage one 33KB emb tile image into LDS at dstbase (linear, wave-uniform base)
#define STAGE_EMB(DSTBASE, TILE)                                                  \
    {                                                                             \
        const char* gsrc = blob + (size_t)(TILE) * BLOB_TILE;                     \
        char* ldst = (DSTBASE) + ((tid >> 6) << 10);                              \
        const char* g = gsrc + tid * 16;                                          \
        _Pragma("unroll")                                                         \
        for (int q = 0; q < 8; ++q)                                               \
            gload_lds16(g + q * 4096, ldst + q * 4096);                           \
        if (tid < 32) gload_lds16(gsrc + 32768 + tid * 16, (DSTBASE) + 32768);    \
    }

// ---- pass 1: per-row stats (argmin, Z, S1') over a 2048-wide k split ----
__global__ __launch_bounds__(256) void k_pass1(
    const float* __restrict__ z, const char* __restrict__ blob,
    float* __restrict__ Zpart, float* __restrict__ S1part,
    float* __restrict__ dmpart, int* __restrict__ impart)
{
    __shared__ __align__(16) char smem[BLOB_TILE];
    __shared__ float zzsh[64];
    float (*zt)[68] = (float (*)[68])smem;

    const int tid = threadIdx.x;
    const int panel = blockIdx.x >> 2;
    const int ks = blockIdx.x & 3;
    const int n0 = panel * 64;

    { // stage z panel (64 rows): zt[d][r]
        const int c = tid & 63, rq = (tid >> 6) * 16;
        const float* src = z + ((n0 >> 10) * 64 + c) * 1024 + (n0 & 1023) + rq;
#pragma unroll
        for (int i = 0; i < 4; ++i) {
            float4 v = ((const float4*)src)[i];
            *(float4*)&zt[c][rq + 4 * i] = v;
        }
    }
    __syncthreads();
    if (tid < 64) { // numpy pairwise-8 ||z||^2
        float r8[8];
#pragma unroll
        for (int j = 0; j < 8; ++j) { float v = zt[j][tid]; r8[j] = __fmul_rn(v, v); }
#pragma unroll
        for (int i = 8; i < 64; i += 8)
#pragma unroll
            for (int j = 0; j < 8; ++j) {
                float v = zt[i + j][tid];
                r8[j] = __fadd_rn(r8[j], __fmul_rn(v, v));
            }
        float s01 = __fadd_rn(r8[0], r8[1]), s23 = __fadd_rn(r8[2], r8[3]);
        float s45 = __fadd_rn(r8[4], r8[5]), s67 = __fadd_rn(r8[6], r8[7]);
        zzsh[tid] = __fadd_rn(__fadd_rn(s01, s23), __fadd_rn(s45, s67));
    }

    const int ln = tid & 63, wv = tid >> 6;
    const int lr = ln & 15, lg = ln >> 4;

    short8v Ah[2], Al[2];
#pragma unroll
    for (int s = 0; s < 2; ++s) {
        const int row = wv * 16 + lr;
        const int db = s * 32 + lg * 8;
#pragma unroll
        for (int j = 0; j < 8; ++j) {
            float f = zt[db + j][row];
            unsigned short hb = f2bf_rne(f);
            float hf = __uint_as_float((unsigned)hb << 16);
            Ah[s][j] = (short)hb;
            Al[s][j] = (short)f2bf_rne(f - hf);
        }
    }
    __syncthreads();   // zt reads done; smem free for tile images

    float zzr[4];
#pragma unroll
    for (int rg = 0; rg < 4; ++rg) zzr[rg] = zzsh[wv * 16 + lg * 4 + rg];

    STAGE_EMB(smem, ks * 16);    // prefetch first tile

    float Zp[4] = {0.f, 0.f, 0.f, 0.f}, S1p[4] = {0.f, 0.f, 0.f, 0.f};
    float dmin[4] = {FLT_MAX, FLT_MAX, FLT_MAX, FLT_MAX};
    int imin[4] = {0, 0, 0, 0};

    for (int it = 0; it < 16; ++it) {
        const int kbase = ks * 2048 + it * 128;
        __syncthreads();   // drains vmcnt (tile landed) + barrier

        f32x4 acc[8];
#pragma unroll
        for (int f = 0; f < 8; ++f) { f32x4 zv = {0.f, 0.f, 0.f, 0.f}; acc[f] = zv; }

#pragma unroll
        for (int f = 0; f < 8; ++f) {
            const int rr = f * 16 + lr;
            const int sw2 = (rr & 7) << 4;
            short8v Bh[2], Bl[2];
#pragma unroll
            for (int s = 0; s < 2; ++s) {
                const int byt = (rr * 128 + s * 64 + lg * 16) ^ sw2;
                Bh[s] = *(const short8v*)(smem + byt);
                Bl[s] = *(const short8v*)(smem + 16384 + byt);
            }
#pragma unroll
            for (int s = 0; s < 2; ++s) {
                acc[f] = __builtin_amdgcn_mfma_f32_16x16x32_bf16(Ah[s], Bh[s], acc[f], 0, 0, 0);
                acc[f] = __builtin_amdgcn_mfma_f32_16x16x32_bf16(Ah[s], Bl[s], acc[f], 0, 0, 0);
                acc[f] = __builtin_amdgcn_mfma_f32_16x16x32_bf16(Al[s], Bh[s], acc[f], 0, 0, 0);
                acc[f] = __builtin_amdgcn_mfma_f32_16x16x32_bf16(Al[s], Bl[s], acc[f], 0, 0, 0);
            }
        }

        float e2v[8];
#pragma unroll
        for (int f = 0; f < 8; ++f)
            e2v[f] = *(const float*)(smem + 32768 + (f * 16 + lr) * 4);

        __syncthreads();               // all waves done reading this tile
        if (it < 15) STAGE_EMB(smem, ks * 16 + it + 1);   // prefetch next under epilogue

#pragma unroll
        for (int f = 0; f < 8; ++f) {
            const float c2 = e2v[f] * C100L2E;
            const int kk = kbase + f * 16 + lr;
#pragma unroll
            for (int rg = 0; rg < 4; ++rg) {
                const float sdot = acc[f][rg];
                const float t = fmaf(sdot, C200L2E, -c2);
                const float ex = __builtin_amdgcn_exp2f(t);
                Zp[rg] += ex;
                S1p[rg] = fmaf(t, ex, S1p[rg]);
                const float dnp = __fsub_rn(__fadd_rn(zzr[rg], e2v[f]),
                                            __fmul_rn(2.f, sdot));
                if (dnp < dmin[rg]) { dmin[rg] = dnp; imin[rg] = kk; }
            }
        }
    }

#pragma unroll
    for (int msk = 1; msk < 16; msk <<= 1) {
#pragma unroll
        for (int rg = 0; rg < 4; ++rg) {
            float d2 = __shfl_xor(dmin[rg], msk, 16);
            int i2 = __shfl_xor(imin[rg], msk, 16);
            float Z2 = __shfl_xor(Zp[rg], msk, 16);
            float s2 = __shfl_xor(S1p[rg], msk, 16);
            if (d2 < dmin[rg] || (d2 == dmin[rg] && i2 < imin[rg])) {
                dmin[rg] = d2; imin[rg] = i2;
            }
            Zp[rg] += Z2;
            S1p[rg] += s2;
        }
    }
    if (lr == 0) {
#pragma unroll
        for (int rg = 0; rg < 4; ++rg) {
            const int n = n0 + wv * 16 + lg * 4 + rg;
            Zpart[ks * 16384 + n] = Zp[rg];
            S1part[ks * 16384 + n] = S1p[rg];
            dmpart[ks * 16384 + n] = dmin[rg];
            impart[ks * 16384 + n] = imin[rg];
        }
    }
}

__global__ __launch_bounds__(256) void k_rowred(
    const float* __restrict__ Zpart, const float* __restrict__ S1part,
    const float* __restrict__ dmpart, const int* __restrict__ impart,
    float* __restrict__ invZ, int* __restrict__ minidx,
    float* __restrict__ out_idx, double* __restrict__ pse_sum)
{
    const int n = blockIdx.x * 256 + threadIdx.x;
    float Z = __fadd_rn(__fadd_rn(Zpart[n], Zpart[16384 + n]),
                        __fadd_rn(Zpart[32768 + n], Zpart[49152 + n]));
    float S1 = __fadd_rn(__fadd_rn(S1part[n], S1part[16384 + n]),
                         __fadd_rn(S1part[32768 + n], S1part[49152 + n]));
    float dm = dmpart[n];
    int im = impart[n];
#pragma unroll
    for (int ksp = 1; ksp < 4; ++ksp) {
        float d2 = dmpart[ksp * 16384 + n];
        int i2 = impart[ksp * 16384 + n];
        if (d2 < dm || (d2 == dm && i2 < im)) { dm = d2; im = i2; }
    }
    minidx[n] = im;
    out_idx[n] = (float)im;
    float iz = 1.0f / Z;
    invZ[n] = iz;
    double h = log((double)Z) - LN2 * (double)S1 * (double)iz;
#pragma unroll
    for (int m = 32; m > 0; m >>= 1) h += __shfl_xor(h, m, 64);
    if ((threadIdx.x & 63) == 0) atomicAdd(pse_sum, h);
}

// ---- pass 2 (k-major): block owns k-tile kt (128 codes) x 1024-row n range.
// Emb tile staged once; z staged per 64-row panel; acc in REGISTERS; atomics
// to avg_acc only at block end (kills the per-iter chip-wide atomic hammering).
__global__ __launch_bounds__(256) void k_pass2(
    const float* __restrict__ z, const char* __restrict__ blob,
    const float* __restrict__ invZ, float* __restrict__ avg_acc)
{
    __shared__ __align__(16) char smem[51456];
    // [0, 33792)      emb tile image (hi 16K | lo 16K | e2 512)
    // [33792, 51200)  zt[64][68] f32  (z panel, d-major)
    // [51200, 51456)  izrow[64] f32
    char* regB = smem + 33792;
    float* izC = (float*)(smem + 51200);

    const int tid = threadIdx.x;
    const int kt = blockIdx.x & 63;
    const int ns = blockIdx.x >> 6;    // 0..15, n range ns*1024..+1023
    const int ln = tid & 63, wv = tid >> 6;
    const int lr = ln & 15, lg = ln >> 4;

    // precompute z-panel staging slots: wave region = 16 rows x 272B (68 f32)
    const char* zsrc[5]; char* zdst[5]; bool zok[5];
#pragma unroll
    for (int q = 0; q < 5; ++q) {
        const int off_w = q * 1024 + ln * 16;
        const int c_local = off_w / 272;
        const int rem = off_w - c_local * 272;
        zok[q] = (off_w < 4352) && (rem < 256);
        const int r4f = rem >> 2;
        zsrc[q] = (const char*)(z + (ns * 64 + wv * 16 + c_local) * 1024 + r4f);
        zdst[q] = regB + wv * 4352 + q * 1024;
    }

    STAGE_EMB(smem, kt);
#pragma unroll
    for (int q = 0; q < 5; ++q)
        if (zok[q]) gload_lds16(zsrc[q], zdst[q]);
    if (tid < 16)
        gload_lds16((const char*)(invZ + ns * 1024) + tid * 16, izC);
    __syncthreads();   // drains all staging

    float e2v[8];
#pragma unroll
    for (int f = 0; f < 8; ++f)
        e2v[f] = *(const float*)(smem + 32768 + (f * 16 + lr) * 4);

    float acck[8] = {0.f, 0.f, 0.f, 0.f, 0.f, 0.f, 0.f, 0.f};

    for (int it = 0; it < 16; ++it) {
        // A-frags from z panel
        short8v Ah[2], Al[2];
#pragma unroll
        for (int s = 0; s < 2; ++s) {
            const int row = wv * 16 + lr;
            const int db = s * 32 + lg * 8;
#pragma unroll
            for (int j = 0; j < 8; ++j) {
                float f = *(const float*)(regB + (db + j) * 272 + row * 4);
                unsigned short hb = f2bf_rne(f);
                float hf = __uint_as_float((unsigned)hb << 16);
                Ah[s][j] = (short)hb;
                Al[s][j] = (short)f2bf_rne(f - hf);
            }
        }
        float izr[4];
#pragma unroll
        for (int rg = 0; rg < 4; ++rg) izr[rg] = izC[wv * 16 + lg * 4 + rg];

        f32x4 acc[8];
#pragma unroll
        for (int f = 0; f < 8; ++f) { f32x4 zv = {0.f, 0.f, 0.f, 0.f}; acc[f] = zv; }

#pragma unroll
        for (int f = 0; f < 8; ++f) {
            const int rr = f * 16 + lr;
            const int sw2 = (rr & 7) << 4;
            short8v Bh[2], Bl[2];
#pragma unroll
            for (int s = 0; s < 2; ++s) {
                const int byt = (rr * 128 + s * 64 + lg * 16) ^ sw2;
                Bh[s] = *(const short8v*)(smem + byt);
                Bl[s] = *(const short8v*)(smem + 16384 + byt);
            }
#pragma unroll
            for (int s = 0; s < 2; ++s) {
                acc[f] = __builtin_amdgcn_mfma_f32_16x16x32_bf16(Ah[s], Bh[s], acc[f], 0, 0, 0);
                acc[f] = __builtin_amdgcn_mfma_f32_16x16x32_bf16(Ah[s], Bl[s], acc[f], 0, 0, 0);
                acc[f] = __builtin_amdgcn_mfma_f32_16x16x32_bf16(Al[s], Bh[s], acc[f], 0, 0, 0);
                acc[f] = __builtin_amdgcn_mfma_f32_16x16x32_bf16(Al[s], Bl[s], acc[f], 0, 0, 0);
            }
        }

        __syncthreads();   // all waves done reading z panel + izrow
        if (it < 15) {
#pragma unroll
            for (int q = 0; q < 5; ++q)
                if (zok[q]) gload_lds16(zsrc[q] + (it + 1) * 256, zdst[q]);
            if (tid < 16)
                gload_lds16((const char*)(invZ + ns * 1024 + (it + 1) * 64) + tid * 16, izC);
        }

        // register epilogue (overlaps staging)
#pragma unroll
        for (int f = 0; f < 8; ++f) {
            const float c2 = e2v[f] * C100L2E;
#pragma unroll
            for (int rg = 0; rg < 4; ++rg) {
                const float t = fmaf(acc[f][rg], C200L2E, -c2);
                const float ex = __builtin_amdgcn_exp2f(t);
                acck[f] = fmaf(ex, izr[rg], acck[f]);
            }
        }
        __syncthreads();   // drains staging before next A-build
    }

    // one atomic round per wave at the very end
#pragma unroll
    for (int f = 0; f < 8; ++f) {
        float cs = acck[f];
        cs += __shfl_xor(cs, 16, 64);
        cs += __shfl_xor(cs, 32, 64);
        if (lg == 0) atomicAdd(&avg_acc[kt * 128 + f * 16 + lr], cs);
    }
}

// gather quantized output + per-block loss partial (no contended atomics)
__global__ __launch_bounds__(256) void k_quant(
    const float* __restrict__ z, const float* __restrict__ emb,
    const int* __restrict__ minidx, float* __restrict__ out,
    double* __restrict__ loss_part)
{
    __shared__ float lred[4];
    const int o = blockIdx.x * 256 + threadIdx.x;
    const int n = ((o >> 16) << 10) + (o & 1023);
    const int c = (o >> 10) & 63;
    const int idx = minidx[n];
    const float e = emb[idx * 64 + c];
    const float zv = z[o];
    out[o] = e;
    float d = e - zv;
    float sq = d * d;
#pragma unroll
    for (int m = 32; m > 0; m >>= 1) sq += __shfl_xor(sq, m, 64);
    if ((threadIdx.x & 63) == 0) lred[threadIdx.x >> 6] = sq;
    __syncthreads();
    if (threadIdx.x == 0)
        loss_part[blockIdx.x] = (double)lred[0] + (double)lred[1]
                              + (double)lred[2] + (double)lred[3];
}

__global__ __launch_bounds__(256) void k_final(
    const float* __restrict__ avg_acc, const double* __restrict__ pse_sum,
    const double* __restrict__ loss_part, float* __restrict__ out)
{
    __shared__ double red[256];
    const int tid = threadIdx.x;

    double lsum = 0.0;
    for (int k = tid; k < 4096; k += 256) lsum += loss_part[k];
    red[tid] = lsum;
    __syncthreads();
    for (int s = 128; s > 0; s >>= 1) {
        if (tid < s) red[tid] += red[tid + s];
        __syncthreads();
    }
    double ltot = red[0];
    __syncthreads();

    double local = 0.0;
    for (int k = tid; k < 8192; k += 256) {
        float p = avg_acc[k] * (1.0f / 16384.0f);
        float cl = fmaxf(p, 1e-5f);
        local += (double)(-p * logf(cl));
    }
    red[tid] = local;
    __syncthreads();
    for (int s = 128; s > 0; s >>= 1) {
        if (tid < s) red[tid] += red[tid + s];
        __syncthreads();
    }
    if (tid == 0) {
        double ce = red[0];
        double pse = pse_sum[0] / 16384.0;
        out[1048576] = (float)(1.25 * ltot / 1048576.0);
        out[1048577] = (float)(pse - ce);
    }
}

extern "C" void kernel_launch(void* const* d_in, const int* in_sizes, int n_in,
                              void* d_out, int out_size, void* d_ws, size_t ws_size,
                              hipStream_t stream) {
    const float* z = (const float*)d_in[0];
    const float* emb = (const float*)d_in[1];
    float* out = (float*)d_out;
    char* ws = (char*)d_ws;
    char* blob = ws + OFF_BLOB;
    float* invZ = (float*)(ws + OFF_INVZ);
    int* minidx = (int*)(ws + OFF_MINIDX);
    float* avg_acc = (float*)(ws + OFF_AVG);
    double* pse_sum = (double*)(ws + OFF_PSE);
    float* Zpart = (float*)(ws + OFF_ZPART);
    float* S1part = (float*)(ws + OFF_S1PART);
    float* dmpart = (float*)(ws + OFF_DMPART);
    int* impart = (int*)(ws + OFF_IMPART);
    double* loss_part = (double*)(ws + OFF_LOSSP);

    // zero avg_acc + pse_sum every launch (no cross-replay state)
    hipMemsetAsync(ws + OFF_AVG, 0, 32768 + 16, stream);

    k_prep<<<32, 256, 0, stream>>>(emb, blob);
    k_pass1<<<1024, 256, 0, stream>>>(z, blob, Zpart, S1part, dmpart, impart);
    k_rowred<<<64, 256, 0, stream>>>(Zpart, S1part, dmpart, impart,
                                     invZ, minidx, out + 1048578, pse_sum);
    k_pass2<<<1024, 256, 0, stream>>>(z, blob, invZ, avg_acc);
    k_quant<<<4096, 256, 0, stream>>>(z, emb, minidx, out, loss_part);
    k_final<<<1, 256, 0, stream>>>(avg_acc, pse_sum, loss_part, out);
}

// Round 7
// 187.492 us; speedup vs baseline: 5.0114x; 1.0596x over previous
//
#include <hip/hip_runtime.h>
#include <cfloat>

// z:   [16, 64, 32, 32] f32 -> N = 16384 rows of dim 64 (row n = b*1024 + hw)
// emb: [8192, 64] f32
// out (f32): quantized [1048576] | loss [1] | entropy_aux [1] | min_indices [16384]
//
// s = z.e via 4-term bf16-split MFMA (zh+zl)(eh+el), f32 accumulate.
// argmin on numpy-rounding-emulated d = fl(fl(zz+ee) - fl(2s)); 2s is exact.
//
// z_blob (bf16 hi/lo A-fragment images, 256 panels x 16KB = 4MB) is written by
// k_pass1 (ks==0 blocks) INTO d_out's quantized region and consumed by k_pass2;
// k_quant later overwrites that region with the real output (stream-ordered).

typedef __attribute__((ext_vector_type(8))) short short8v;   // 8 bf16
typedef __attribute__((ext_vector_type(4))) float f32x4;

#define C100L2E 144.26950408889634f   // 100*log2(e)
#define C200L2E 288.53900817779268f   // 200*log2(e)
#define LN2 0.6931471805599453

// ws layout (bytes):
#define BLOB_TILE 33792               // 16K hi bf16 + 16K lo bf16 + 512B e2 (+pad)
#define OFF_BLOB   0                  // 64 tiles * 33792 = 2162688
#define OFF_INVZ   2162688            // f32[16384]
#define OFF_MINIDX 2228224            // i32[16384]
#define OFF_AVG    2293760            // f32[8192]   (zeroed each launch)
#define OFF_PSE    2326528            // double      (zeroed each launch)
#define OFF_ZPART  2326544            // f32[4][16384]
#define OFF_S1PART (OFF_ZPART + 262144)
#define OFF_DMPART (OFF_S1PART + 262144)
#define OFF_IMPART (OFF_DMPART + 262144)
#define OFF_LOSSP  (OFF_IMPART + 262144)  // dbl[4096] fully rewritten each launch

__device__ __forceinline__ unsigned short f2bf_rne(float f) {
    unsigned u = __float_as_uint(f);
    u = (u + 0x7fffu + ((u >> 16) & 1u)) >> 16;
    return (unsigned short)u;
}

__device__ __forceinline__ void gload_lds16(const void* g, void* l) {
    __builtin_amdgcn_global_load_lds(
        (const __attribute__((address_space(1))) unsigned int*)g,
        (__attribute__((address_space(3))) unsigned int*)l, 16, 0, 0);
}

// Build pre-swizzled bf16 hi/lo emb tile images + per-tile e2 (numpy pairwise-8).
__global__ __launch_bounds__(256) void k_prep(const float* __restrict__ emb,
                                              char* __restrict__ blob) {
    const int k = blockIdx.x * 256 + threadIdx.x;   // 8192 rows
    const float* row = emb + k * 64;
    float fv[64];
#pragma unroll
    for (int i = 0; i < 16; ++i) {
        float4 v = ((const float4*)row)[i];
        fv[4 * i] = v.x; fv[4 * i + 1] = v.y; fv[4 * i + 2] = v.z; fv[4 * i + 3] = v.w;
    }
    float r8[8];
#pragma unroll
    for (int j = 0; j < 8; ++j) r8[j] = __fmul_rn(fv[j], fv[j]);
#pragma unroll
    for (int i = 8; i < 64; i += 8)
#pragma unroll
        for (int j = 0; j < 8; ++j)
            r8[j] = __fadd_rn(r8[j], __fmul_rn(fv[i + j], fv[i + j]));
    float s01 = __fadd_rn(r8[0], r8[1]), s23 = __fadd_rn(r8[2], r8[3]);
    float s45 = __fadd_rn(r8[4], r8[5]), s67 = __fadd_rn(r8[6], r8[7]);
    float e2 = __fadd_rn(__fadd_rn(s01, s23), __fadd_rn(s45, s67));

    char* tb = blob + (size_t)(k >> 7) * BLOB_TILE;
    const int r = k & 127;
    ((float*)(tb + 32768))[r] = e2;
    const int sw = (r & 7) << 4;
#pragma unroll
    for (int dh = 0; dh < 2; ++dh)
#pragma unroll
        for (int cg = 0; cg < 4; ++cg) {
            short8v hv, lv;
#pragma unroll
            for (int e = 0; e < 8; ++e) {
                float f = fv[dh * 32 + cg * 8 + e];
                unsigned short hb = f2bf_rne(f);
                float hf = __uint_as_float((unsigned)hb << 16);
                hv[e] = (short)hb;
                lv[e] = (short)f2bf_rne(f - hf);
            }
            const int byt = (r * 128 + dh * 64 + cg * 16) ^ sw;
            *(short8v*)(tb + byt) = hv;
            *(short8v*)(tb + 16384 + byt) = lv;
        }
}

// stage one 33KB emb tile image into LDS at dstbase (linear, wave-uniform base)
#define STAGE_EMB(DSTBASE, TILE)                                                  \
    {                                                                             \
        const char* gsrc = blob + (size_t)(TILE) * BLOB_TILE;                     \
        char* ldst = (DSTBASE) + ((tid >> 6) << 10);                              \
        const char* g = gsrc + tid * 16;                                          \
        _Pragma("unroll")                                                         \
        for (int q = 0; q < 8; ++q)                                               \
            gload_lds16(g + q * 4096, ldst + q * 4096);                           \
        if (tid < 32) gload_lds16(gsrc + 32768 + tid * 16, (DSTBASE) + 32768);    \
    }

// ---- pass 1: per-row stats (argmin, Z, S1') over a 2048-wide k split ----
// ks==0 blocks additionally store their A-fragments to z_blob for pass 2.
__global__ __launch_bounds__(256) void k_pass1(
    const float* __restrict__ z, const char* __restrict__ blob,
    char* __restrict__ zblob,
    float* __restrict__ Zpart, float* __restrict__ S1part,
    float* __restrict__ dmpart, int* __restrict__ impart)
{
    __shared__ __align__(16) char smem[BLOB_TILE];
    __shared__ float zzsh[64];
    float (*zt)[68] = (float (*)[68])smem;

    const int tid = threadIdx.x;
    const int panel = blockIdx.x >> 2;
    const int ks = blockIdx.x & 3;
    const int n0 = panel * 64;

    { // stage z panel (64 rows): zt[d][r]
        const int c = tid & 63, rq = (tid >> 6) * 16;
        const float* src = z + ((n0 >> 10) * 64 + c) * 1024 + (n0 & 1023) + rq;
#pragma unroll
        for (int i = 0; i < 4; ++i) {
            float4 v = ((const float4*)src)[i];
            *(float4*)&zt[c][rq + 4 * i] = v;
        }
    }
    __syncthreads();
    if (tid < 64) { // numpy pairwise-8 ||z||^2
        float r8[8];
#pragma unroll
        for (int j = 0; j < 8; ++j) { float v = zt[j][tid]; r8[j] = __fmul_rn(v, v); }
#pragma unroll
        for (int i = 8; i < 64; i += 8)
#pragma unroll
            for (int j = 0; j < 8; ++j) {
                float v = zt[i + j][tid];
                r8[j] = __fadd_rn(r8[j], __fmul_rn(v, v));
            }
        float s01 = __fadd_rn(r8[0], r8[1]), s23 = __fadd_rn(r8[2], r8[3]);
        float s45 = __fadd_rn(r8[4], r8[5]), s67 = __fadd_rn(r8[6], r8[7]);
        zzsh[tid] = __fadd_rn(__fadd_rn(s01, s23), __fadd_rn(s45, s67));
    }

    const int ln = tid & 63, wv = tid >> 6;
    const int lr = ln & 15, lg = ln >> 4;

    short8v Ah[2], Al[2];
#pragma unroll
    for (int s = 0; s < 2; ++s) {
        const int row = wv * 16 + lr;
        const int db = s * 32 + lg * 8;
#pragma unroll
        for (int j = 0; j < 8; ++j) {
            float f = zt[db + j][row];
            unsigned short hb = f2bf_rne(f);
            float hf = __uint_as_float((unsigned)hb << 16);
            Ah[s][j] = (short)hb;
            Al[s][j] = (short)f2bf_rne(f - hf);
        }
    }

    // publish A-fragments for pass 2 (one ks does it; plain linear layout)
    if (ks == 0) {
        char* tb = zblob + (size_t)panel * 16384;
        const int rowp = wv * 16 + lr;
#pragma unroll
        for (int s = 0; s < 2; ++s) {
            const int byt = rowp * 128 + s * 64 + lg * 16;
            *(short8v*)(tb + byt) = Ah[s];
            *(short8v*)(tb + 8192 + byt) = Al[s];
        }
    }
    __syncthreads();   // zt reads done; smem free for tile images

    float zzr[4];
#pragma unroll
    for (int rg = 0; rg < 4; ++rg) zzr[rg] = zzsh[wv * 16 + lg * 4 + rg];

    STAGE_EMB(smem, ks * 16);    // prefetch first tile

    float Zp[4] = {0.f, 0.f, 0.f, 0.f}, S1p[4] = {0.f, 0.f, 0.f, 0.f};
    float dmin[4] = {FLT_MAX, FLT_MAX, FLT_MAX, FLT_MAX};
    int imin[4] = {0, 0, 0, 0};

    for (int it = 0; it < 16; ++it) {
        const int kbase = ks * 2048 + it * 128;
        __syncthreads();   // drains vmcnt (tile landed) + barrier

        f32x4 acc[8];
#pragma unroll
        for (int f = 0; f < 8; ++f) { f32x4 zv = {0.f, 0.f, 0.f, 0.f}; acc[f] = zv; }

#pragma unroll
        for (int f = 0; f < 8; ++f) {
            const int rr = f * 16 + lr;
            const int sw2 = (rr & 7) << 4;
            short8v Bh[2], Bl[2];
#pragma unroll
            for (int s = 0; s < 2; ++s) {
                const int byt = (rr * 128 + s * 64 + lg * 16) ^ sw2;
                Bh[s] = *(const short8v*)(smem + byt);
                Bl[s] = *(const short8v*)(smem + 16384 + byt);
            }
#pragma unroll
            for (int s = 0; s < 2; ++s) {
                acc[f] = __builtin_amdgcn_mfma_f32_16x16x32_bf16(Ah[s], Bh[s], acc[f], 0, 0, 0);
                acc[f] = __builtin_amdgcn_mfma_f32_16x16x32_bf16(Ah[s], Bl[s], acc[f], 0, 0, 0);
                acc[f] = __builtin_amdgcn_mfma_f32_16x16x32_bf16(Al[s], Bh[s], acc[f], 0, 0, 0);
                acc[f] = __builtin_amdgcn_mfma_f32_16x16x32_bf16(Al[s], Bl[s], acc[f], 0, 0, 0);
            }
        }

        float e2v[8];
#pragma unroll
        for (int f = 0; f < 8; ++f)
            e2v[f] = *(const float*)(smem + 32768 + (f * 16 + lr) * 4);

        __syncthreads();               // all waves done reading this tile
        if (it < 15) STAGE_EMB(smem, ks * 16 + it + 1);   // prefetch next under epilogue

#pragma unroll
        for (int f = 0; f < 8; ++f) {
            const float c2 = e2v[f] * C100L2E;
            const int kk = kbase + f * 16 + lr;
#pragma unroll
            for (int rg = 0; rg < 4; ++rg) {
                const float sdot = acc[f][rg];
                const float t = fmaf(sdot, C200L2E, -c2);
                const float ex = __builtin_amdgcn_exp2f(t);
                Zp[rg] += ex;
                S1p[rg] = fmaf(t, ex, S1p[rg]);
                const float dnp = __fsub_rn(__fadd_rn(zzr[rg], e2v[f]),
                                            __fmul_rn(2.f, sdot));
                if (dnp < dmin[rg]) { dmin[rg] = dnp; imin[rg] = kk; }
            }
        }
    }

#pragma unroll
    for (int msk = 1; msk < 16; msk <<= 1) {
#pragma unroll
        for (int rg = 0; rg < 4; ++rg) {
            float d2 = __shfl_xor(dmin[rg], msk, 16);
            int i2 = __shfl_xor(imin[rg], msk, 16);
            float Z2 = __shfl_xor(Zp[rg], msk, 16);
            float s2 = __shfl_xor(S1p[rg], msk, 16);
            if (d2 < dmin[rg] || (d2 == dmin[rg] && i2 < imin[rg])) {
                dmin[rg] = d2; imin[rg] = i2;
            }
            Zp[rg] += Z2;
            S1p[rg] += s2;
        }
    }
    if (lr == 0) {
#pragma unroll
        for (int rg = 0; rg < 4; ++rg) {
            const int n = n0 + wv * 16 + lg * 4 + rg;
            Zpart[ks * 16384 + n] = Zp[rg];
            S1part[ks * 16384 + n] = S1p[rg];
            dmpart[ks * 16384 + n] = dmin[rg];
            impart[ks * 16384 + n] = imin[rg];
        }
    }
}

__global__ __launch_bounds__(256) void k_rowred(
    const float* __restrict__ Zpart, const float* __restrict__ S1part,
    const float* __restrict__ dmpart, const int* __restrict__ impart,
    float* __restrict__ invZ, int* __restrict__ minidx,
    float* __restrict__ out_idx, double* __restrict__ pse_sum)
{
    const int n = blockIdx.x * 256 + threadIdx.x;
    float Z = __fadd_rn(__fadd_rn(Zpart[n], Zpart[16384 + n]),
                        __fadd_rn(Zpart[32768 + n], Zpart[49152 + n]));
    float S1 = __fadd_rn(__fadd_rn(S1part[n], S1part[16384 + n]),
                         __fadd_rn(S1part[32768 + n], S1part[49152 + n]));
    float dm = dmpart[n];
    int im = impart[n];
#pragma unroll
    for (int ksp = 1; ksp < 4; ++ksp) {
        float d2 = dmpart[ksp * 16384 + n];
        int i2 = impart[ksp * 16384 + n];
        if (d2 < dm || (d2 == dm && i2 < im)) { dm = d2; im = i2; }
    }
    minidx[n] = im;
    out_idx[n] = (float)im;
    float iz = 1.0f / Z;
    invZ[n] = iz;
    double h = log((double)Z) - LN2 * (double)S1 * (double)iz;
#pragma unroll
    for (int m = 32; m > 0; m >>= 1) h += __shfl_xor(h, m, 64);
    if ((threadIdx.x & 63) == 0) atomicAdd(pse_sum, h);
}

// ---- pass 2 (barrier-free): block = k-tile kt (128 codes) x 1024-row n range.
// Emb tile + invZ staged once; A-fragments loaded from z_blob (global, L2)
// straight into registers; m=2 (32 rows/wave); acc in registers; atomics once
// per wave at the end. No barriers inside the loop.
__global__ __launch_bounds__(256) void k_pass2(
    const char* __restrict__ zblob, const char* __restrict__ blob,
    const float* __restrict__ invZ, float* __restrict__ avg_acc)
{
    __shared__ __align__(16) char smem[BLOB_TILE + 4096];
    float* izAll = (float*)(smem + BLOB_TILE);   // [1024] f32

    const int tid = threadIdx.x;
    const int kt = blockIdx.x & 63;
    const int ns = blockIdx.x >> 6;      // 0..15: rows ns*1024 .. +1023
    const int ln = tid & 63, wv = tid >> 6;
    const int lr = ln & 15, lg = ln >> 4;

    STAGE_EMB(smem, kt);
    gload_lds16((const char*)(invZ + ns * 1024) + tid * 16,
                (char*)izAll + (wv << 10));
    __syncthreads();     // only barrier in the kernel

    float e2v[8];
#pragma unroll
    for (int f = 0; f < 8; ++f)
        e2v[f] = *(const float*)(smem + 32768 + (f * 16 + lr) * 4);

    float acck[8] = {0.f, 0.f, 0.f, 0.f, 0.f, 0.f, 0.f, 0.f};

    for (int it = 0; it < 8; ++it) {
        // A-fragments from z_blob: rows it*128 + wv*32 + m*16 + lr
        short8v Ah[2][2], Al[2][2];
        const int p64 = ns * 16 + it * 2 + (wv >> 1);
        const char* tb = zblob + (size_t)p64 * 16384;
#pragma unroll
        for (int m = 0; m < 2; ++m) {
            const int rowp = (wv & 1) * 32 + m * 16 + lr;
#pragma unroll
            for (int s = 0; s < 2; ++s) {
                const int byt = rowp * 128 + s * 64 + lg * 16;
                Ah[m][s] = *(const short8v*)(tb + byt);
                Al[m][s] = *(const short8v*)(tb + 8192 + byt);
            }
        }
        // invZ for this iter's rows
        const int izb = it * 128 + wv * 32 + lg * 4;
        float4 iz0 = *(const float4*)&izAll[izb];
        float4 iz1 = *(const float4*)&izAll[izb + 16];
        float izr[2][4] = {{iz0.x, iz0.y, iz0.z, iz0.w},
                           {iz1.x, iz1.y, iz1.z, iz1.w}};

        f32x4 acc[2][8];
#pragma unroll
        for (int m = 0; m < 2; ++m)
#pragma unroll
            for (int f = 0; f < 8; ++f) {
                f32x4 zv = {0.f, 0.f, 0.f, 0.f};
                acc[m][f] = zv;
            }

#pragma unroll
        for (int f = 0; f < 8; ++f) {
            const int rr = f * 16 + lr;
            const int sw2 = (rr & 7) << 4;
            short8v Bh[2], Bl[2];
#pragma unroll
            for (int s = 0; s < 2; ++s) {
                const int byt = (rr * 128 + s * 64 + lg * 16) ^ sw2;
                Bh[s] = *(const short8v*)(smem + byt);
                Bl[s] = *(const short8v*)(smem + 16384 + byt);
            }
#pragma unroll
            for (int s = 0; s < 2; ++s)
#pragma unroll
                for (int m = 0; m < 2; ++m) {
                    acc[m][f] = __builtin_amdgcn_mfma_f32_16x16x32_bf16(Ah[m][s], Bh[s], acc[m][f], 0, 0, 0);
                    acc[m][f] = __builtin_amdgcn_mfma_f32_16x16x32_bf16(Ah[m][s], Bl[s], acc[m][f], 0, 0, 0);
                    acc[m][f] = __builtin_amdgcn_mfma_f32_16x16x32_bf16(Al[m][s], Bh[s], acc[m][f], 0, 0, 0);
                    acc[m][f] = __builtin_amdgcn_mfma_f32_16x16x32_bf16(Al[m][s], Bl[s], acc[m][f], 0, 0, 0);
                }
        }

#pragma unroll
        for (int f = 0; f < 8; ++f) {
            const float c2 = e2v[f] * C100L2E;
#pragma unroll
            for (int m = 0; m < 2; ++m)
#pragma unroll
                for (int rg = 0; rg < 4; ++rg) {
                    const float t = fmaf(acc[m][f][rg], C200L2E, -c2);
                    const float ex = __builtin_amdgcn_exp2f(t);
                    acck[f] = fmaf(ex, izr[m][rg], acck[f]);
                }
        }
    }

    // one atomic round per wave
#pragma unroll
    for (int f = 0; f < 8; ++f) {
        float cs = acck[f];
        cs += __shfl_xor(cs, 16, 64);
        cs += __shfl_xor(cs, 32, 64);
        if (lg == 0) atomicAdd(&avg_acc[kt * 128 + f * 16 + lr], cs);
    }
}

// gather quantized output + per-block loss partial (no contended atomics)
__global__ __launch_bounds__(256) void k_quant(
    const float* __restrict__ z, const float* __restrict__ emb,
    const int* __restrict__ minidx, float* __restrict__ out,
    double* __restrict__ loss_part)
{
    __shared__ float lred[4];
    const int o = blockIdx.x * 256 + threadIdx.x;
    const int n = ((o >> 16) << 10) + (o & 1023);
    const int c = (o >> 10) & 63;
    const int idx = minidx[n];
    const float e = emb[idx * 64 + c];
    const float zv = z[o];
    out[o] = e;
    float d = e - zv;
    float sq = d * d;
#pragma unroll
    for (int m = 32; m > 0; m >>= 1) sq += __shfl_xor(sq, m, 64);
    if ((threadIdx.x & 63) == 0) lred[threadIdx.x >> 6] = sq;
    __syncthreads();
    if (threadIdx.x == 0)
        loss_part[blockIdx.x] = (double)lred[0] + (double)lred[1]
                              + (double)lred[2] + (double)lred[3];
}

__global__ __launch_bounds__(256) void k_final(
    const float* __restrict__ avg_acc, const double* __restrict__ pse_sum,
    const double* __restrict__ loss_part, float* __restrict__ out)
{
    __shared__ double red[256];
    const int tid = threadIdx.x;

    double lsum = 0.0;
    for (int k = tid; k < 4096; k += 256) lsum += loss_part[k];
    red[tid] = lsum;
    __syncthreads();
    for (int s = 128; s > 0; s >>= 1) {
        if (tid < s) red[tid] += red[tid + s];
        __syncthreads();
    }
    double ltot = red[0];
    __syncthreads();

    double local = 0.0;
    for (int k = tid; k < 8192; k += 256) {
        float p = avg_acc[k] * (1.0f / 16384.0f);
        float cl = fmaxf(p, 1e-5f);
        local += (double)(-p * logf(cl));
    }
    red[tid] = local;
    __syncthreads();
    for (int s = 128; s > 0; s >>= 1) {
        if (tid < s) red[tid] += red[tid + s];
        __syncthreads();
    }
    if (tid == 0) {
        double ce = red[0];
        double pse = pse_sum[0] / 16384.0;
        out[1048576] = (float)(1.25 * ltot / 1048576.0);
        out[1048577] = (float)(pse - ce);
    }
}

extern "C" void kernel_launch(void* const* d_in, const int* in_sizes, int n_in,
                              void* d_out, int out_size, void* d_ws, size_t ws_size,
                              hipStream_t stream) {
    const float* z = (const float*)d_in[0];
    const float* emb = (const float*)d_in[1];
    float* out = (float*)d_out;
    char* ws = (char*)d_ws;
    char* blob = ws + OFF_BLOB;
    float* invZ = (float*)(ws + OFF_INVZ);
    int* minidx = (int*)(ws + OFF_MINIDX);
    float* avg_acc = (float*)(ws + OFF_AVG);
    double* pse_sum = (double*)(ws + OFF_PSE);
    float* Zpart = (float*)(ws + OFF_ZPART);
    float* S1part = (float*)(ws + OFF_S1PART);
    float* dmpart = (float*)(ws + OFF_DMPART);
    int* impart = (int*)(ws + OFF_IMPART);
    double* loss_part = (double*)(ws + OFF_LOSSP);
    // z_blob scratch lives in d_out's quantized region (exactly 4 MB);
    // k_quant overwrites it afterwards (stream-ordered).
    char* zblob = (char*)d_out;

    // zero avg_acc + pse_sum every launch (no cross-replay state)
    hipMemsetAsync(ws + OFF_AVG, 0, 32768 + 16, stream);

    k_prep<<<32, 256, 0, stream>>>(emb, blob);
    k_pass1<<<1024, 256, 0, stream>>>(z, blob, zblob, Zpart, S1part, dmpart, impart);
    k_rowred<<<64, 256, 0, stream>>>(Zpart, S1part, dmpart, impart,
                                     invZ, minidx, out + 1048578, pse_sum);
    k_pass2<<<1024, 256, 0, stream>>>(zblob, blob, invZ, avg_acc);
    k_quant<<<4096, 256, 0, stream>>>(z, emb, minidx, out, loss_part);
    k_final<<<1, 256, 0, stream>>>(avg_acc, pse_sum, loss_part, out);
}

// Round 8
// 187.297 us; speedup vs baseline: 5.0166x; 1.0010x over previous
//
#include <hip/hip_runtime.h>
#include <cfloat>

// z:   [16, 64, 32, 32] f32 -> N = 16384 rows of dim 64 (row n = b*1024 + hw)
// emb: [8192, 64] f32
// out (f32): quantized [1048576] | loss [1] | entropy_aux [1] | min_indices [16384]
//
// s = z.e via 4-term bf16-split MFMA (zh+zl)(eh+el), f32 accumulate.
// argmin on numpy-rounding-emulated d = fl(fl(zz+ee) - 2s) (2s exact).
//
// z_blob (bf16 hi/lo A-fragment images, 256 panels x 16KB = 4MB) is written by
// k_zprep INTO d_out's quantized region, consumed by k_pass1 and k_pass2;
// k_quant later overwrites that region with the real output (stream-ordered).

typedef __attribute__((ext_vector_type(8))) short short8v;   // 8 bf16
typedef __attribute__((ext_vector_type(4))) float f32x4;

#define C100L2E 144.26950408889634f   // 100*log2(e)
#define C200L2E 288.53900817779268f   // 200*log2(e)
#define LN2 0.6931471805599453

// ws layout (bytes):
#define BLOB_TILE 33792               // 16K hi bf16 + 16K lo bf16 + 512B e2 (+pad)
#define OFF_BLOB   0                  // 64 tiles * 33792 = 2162688
#define OFF_INVZ   2162688            // f32[16384]
#define OFF_MINIDX 2228224            // i32[16384]
#define OFF_AVG    2293760            // f32[8192]   (zeroed each launch)
#define OFF_PSE    2326528            // double      (zeroed each launch)
#define OFF_ZPART  2326544            // f32[4][16384]
#define OFF_S1PART (OFF_ZPART + 262144)
#define OFF_DMPART (OFF_S1PART + 262144)
#define OFF_IMPART (OFF_DMPART + 262144)
#define OFF_LOSSP  (OFF_IMPART + 262144)  // dbl[4096] fully rewritten each launch
#define OFF_ZZ     (OFF_LOSSP + 32768)    // f32[16384] numpy-pairwise ||z||^2

__device__ __forceinline__ unsigned short f2bf_rne(float f) {
    unsigned u = __float_as_uint(f);
    u = (u + 0x7fffu + ((u >> 16) & 1u)) >> 16;
    return (unsigned short)u;
}

__device__ __forceinline__ void gload_lds16(const void* g, void* l) {
    __builtin_amdgcn_global_load_lds(
        (const __attribute__((address_space(1))) unsigned int*)g,
        (__attribute__((address_space(3))) unsigned int*)l, 16, 0, 0);
}

// Build pre-swizzled bf16 hi/lo emb tile images + per-tile e2 (numpy pairwise-8).
__global__ __launch_bounds__(256) void k_prep(const float* __restrict__ emb,
                                              char* __restrict__ blob) {
    const int k = blockIdx.x * 256 + threadIdx.x;   // 8192 rows
    const float* row = emb + k * 64;
    float fv[64];
#pragma unroll
    for (int i = 0; i < 16; ++i) {
        float4 v = ((const float4*)row)[i];
        fv[4 * i] = v.x; fv[4 * i + 1] = v.y; fv[4 * i + 2] = v.z; fv[4 * i + 3] = v.w;
    }
    float r8[8];
#pragma unroll
    for (int j = 0; j < 8; ++j) r8[j] = __fmul_rn(fv[j], fv[j]);
#pragma unroll
    for (int i = 8; i < 64; i += 8)
#pragma unroll
        for (int j = 0; j < 8; ++j)
            r8[j] = __fadd_rn(r8[j], __fmul_rn(fv[i + j], fv[i + j]));
    float s01 = __fadd_rn(r8[0], r8[1]), s23 = __fadd_rn(r8[2], r8[3]);
    float s45 = __fadd_rn(r8[4], r8[5]), s67 = __fadd_rn(r8[6], r8[7]);
    float e2 = __fadd_rn(__fadd_rn(s01, s23), __fadd_rn(s45, s67));

    char* tb = blob + (size_t)(k >> 7) * BLOB_TILE;
    const int r = k & 127;
    ((float*)(tb + 32768))[r] = e2;
    const int sw = (r & 7) << 4;
#pragma unroll
    for (int dh = 0; dh < 2; ++dh)
#pragma unroll
        for (int cg = 0; cg < 4; ++cg) {
            short8v hv, lv;
#pragma unroll
            for (int e = 0; e < 8; ++e) {
                float f = fv[dh * 32 + cg * 8 + e];
                unsigned short hb = f2bf_rne(f);
                float hf = __uint_as_float((unsigned)hb << 16);
                hv[e] = (short)hb;
                lv[e] = (short)f2bf_rne(f - hf);
            }
            const int byt = (r * 128 + dh * 64 + cg * 16) ^ sw;
            *(short8v*)(tb + byt) = hv;
            *(short8v*)(tb + 16384 + byt) = lv;
        }
}

// Build z A-fragment blob (64-row panels: hi 8K | lo 8K, row-sequential bf16)
// + numpy-pairwise ||z||^2. One thread per z row.
__global__ __launch_bounds__(256) void k_zprep(const float* __restrict__ z,
                                               char* __restrict__ zblob,
                                               float* __restrict__ zz) {
    const int r = blockIdx.x * 256 + threadIdx.x;   // 16384 rows
    const float* src = z + (r >> 10) * 65536 + (r & 1023);
    float fv[64];
#pragma unroll
    for (int c = 0; c < 64; ++c) fv[c] = src[c * 1024];

    float r8[8];
#pragma unroll
    for (int j = 0; j < 8; ++j) r8[j] = __fmul_rn(fv[j], fv[j]);
#pragma unroll
    for (int i = 8; i < 64; i += 8)
#pragma unroll
        for (int j = 0; j < 8; ++j)
            r8[j] = __fadd_rn(r8[j], __fmul_rn(fv[i + j], fv[i + j]));
    float s01 = __fadd_rn(r8[0], r8[1]), s23 = __fadd_rn(r8[2], r8[3]);
    float s45 = __fadd_rn(r8[4], r8[5]), s67 = __fadd_rn(r8[6], r8[7]);
    zz[r] = __fadd_rn(__fadd_rn(s01, s23), __fadd_rn(s45, s67));

    char* tb = zblob + (size_t)(r >> 6) * 16384;
    const int rowp = r & 63;
#pragma unroll
    for (int cg = 0; cg < 8; ++cg) {
        short8v hv, lv;
#pragma unroll
        for (int e = 0; e < 8; ++e) {
            float f = fv[cg * 8 + e];
            unsigned short hb = f2bf_rne(f);
            float hf = __uint_as_float((unsigned)hb << 16);
            hv[e] = (short)hb;
            lv[e] = (short)f2bf_rne(f - hf);
        }
        *(short8v*)(tb + rowp * 128 + cg * 16) = hv;
        *(short8v*)(tb + 8192 + rowp * 128 + cg * 16) = lv;
    }
}

// stage one 33KB emb tile image into LDS, 256-thread version (pass 2)
#define STAGE_EMB(DSTBASE, TILE)                                                  \
    {                                                                             \
        const char* gsrc = blob + (size_t)(TILE) * BLOB_TILE;                     \
        char* ldst = (DSTBASE) + ((tid >> 6) << 10);                              \
        const char* g = gsrc + tid * 16;                                          \
        _Pragma("unroll")                                                         \
        for (int q = 0; q < 8; ++q)                                               \
            gload_lds16(g + q * 4096, ldst + q * 4096);                           \
        if (tid < 32) gload_lds16(gsrc + 32768 + tid * 16, (DSTBASE) + 32768);    \
    }

// 512-thread version (pass 1): each wave stages its 4KB chunk
#define STAGE512(DSTBASE, TILE)                                                   \
    {                                                                             \
        const char* gsrc = blob + (size_t)(TILE) * BLOB_TILE;                     \
        char* ldst = (DSTBASE) + ((tid >> 6) << 12);                              \
        const char* g = gsrc + ((tid >> 6) << 12) + (tid & 63) * 16;              \
        _Pragma("unroll")                                                         \
        for (int q = 0; q < 4; ++q)                                               \
            gload_lds16(g + q * 1024, ldst + q * 1024);                           \
        if (tid < 32) gload_lds16(gsrc + 32768 + tid * 16, (DSTBASE) + 32768);    \
    }

// ---- pass 1 v2: 8 waves x 16 rows, double-buffered emb tiles, 1 barrier/iter.
// A-fragments + zz from k_zprep; per-row stats over a 2048-wide k split.
__global__ __launch_bounds__(512) void k_pass1(
    const char* __restrict__ zblob, const char* __restrict__ blob,
    const float* __restrict__ zz,
    float* __restrict__ Zpart, float* __restrict__ S1part,
    float* __restrict__ dmpart, int* __restrict__ impart)
{
    __shared__ __align__(16) char smem[2 * BLOB_TILE];

    const int tid = threadIdx.x;
    const int panel = blockIdx.x >> 2;
    const int ks = blockIdx.x & 3;
    const int n0 = panel * 128;

    const int ln = tid & 63, wv = tid >> 6;
    const int lr = ln & 15, lg = ln >> 4;

    // A-fragments from zblob (registers for the whole kernel)
    short8v Ah[2], Al[2];
    {
        const int p64 = (n0 >> 6) + (wv >> 2);
        const int rowp = (wv & 3) * 16 + lr;
        const char* tb = zblob + (size_t)p64 * 16384;
#pragma unroll
        for (int s = 0; s < 2; ++s) {
            const int byt = rowp * 128 + s * 64 + lg * 16;
            Ah[s] = *(const short8v*)(tb + byt);
            Al[s] = *(const short8v*)(tb + 8192 + byt);
        }
    }
    float zzr[4];
#pragma unroll
    for (int rg = 0; rg < 4; ++rg)
        zzr[rg] = zz[n0 + wv * 16 + lg * 4 + rg];

    STAGE512(smem, ks * 16);    // prologue: stage tile 0 into buf 0

    float Zp[4] = {0.f, 0.f, 0.f, 0.f}, S1p[4] = {0.f, 0.f, 0.f, 0.f};
    float dmin[4] = {FLT_MAX, FLT_MAX, FLT_MAX, FLT_MAX};
    int imin[4] = {0, 0, 0, 0};

    for (int it = 0; it < 16; ++it) {
        const int kbase = ks * 2048 + it * 128;
        __syncthreads();   // buf[it&1] staged (each wave drained vmcnt before entering)
        const char* bb = smem + (it & 1) * BLOB_TILE;
        if (it < 15) STAGE512(smem + ((it + 1) & 1) * BLOB_TILE, ks * 16 + it + 1);

        f32x4 acc[8];
#pragma unroll
        for (int f = 0; f < 8; ++f) { f32x4 zv = {0.f, 0.f, 0.f, 0.f}; acc[f] = zv; }

#pragma unroll
        for (int f = 0; f < 8; ++f) {
            const int rr = f * 16 + lr;
            const int sw2 = (rr & 7) << 4;
            short8v Bh[2], Bl[2];
#pragma unroll
            for (int s = 0; s < 2; ++s) {
                const int byt = (rr * 128 + s * 64 + lg * 16) ^ sw2;
                Bh[s] = *(const short8v*)(bb + byt);
                Bl[s] = *(const short8v*)(bb + 16384 + byt);
            }
#pragma unroll
            for (int s = 0; s < 2; ++s) {
                acc[f] = __builtin_amdgcn_mfma_f32_16x16x32_bf16(Ah[s], Bh[s], acc[f], 0, 0, 0);
                acc[f] = __builtin_amdgcn_mfma_f32_16x16x32_bf16(Ah[s], Bl[s], acc[f], 0, 0, 0);
                acc[f] = __builtin_amdgcn_mfma_f32_16x16x32_bf16(Al[s], Bh[s], acc[f], 0, 0, 0);
                acc[f] = __builtin_amdgcn_mfma_f32_16x16x32_bf16(Al[s], Bl[s], acc[f], 0, 0, 0);
            }
        }

#pragma unroll
        for (int f = 0; f < 8; ++f) {
            const float e2v = *(const float*)(bb + 32768 + (f * 16 + lr) * 4);
            const float c2 = e2v * C100L2E;
            const int kk = kbase + f * 16 + lr;
#pragma unroll
            for (int rg = 0; rg < 4; ++rg) {
                const float sdot = acc[f][rg];
                const float t = fmaf(sdot, C200L2E, -c2);
                const float ex = __builtin_amdgcn_exp2f(t);
                Zp[rg] += ex;
                S1p[rg] = fmaf(t, ex, S1p[rg]);
                // dnp = fl(fl(zz+ee) - 2*sdot); fma of exact product == sub rounding
                const float pre = __fadd_rn(zzr[rg], e2v);
                const float dnp = fmaf(-2.f, sdot, pre);
                if (dnp < dmin[rg]) { dmin[rg] = dnp; imin[rg] = kk; }
            }
        }
    }

    // reduce across the 16 lr lanes; lex tiebreak (min d, then min idx)
#pragma unroll
    for (int msk = 1; msk < 16; msk <<= 1) {
#pragma unroll
        for (int rg = 0; rg < 4; ++rg) {
            float d2 = __shfl_xor(dmin[rg], msk, 16);
            int i2 = __shfl_xor(imin[rg], msk, 16);
            float Z2 = __shfl_xor(Zp[rg], msk, 16);
            float s2 = __shfl_xor(S1p[rg], msk, 16);
            if (d2 < dmin[rg] || (d2 == dmin[rg] && i2 < imin[rg])) {
                dmin[rg] = d2; imin[rg] = i2;
            }
            Zp[rg] += Z2;
            S1p[rg] += s2;
        }
    }
    if (lr == 0) {
#pragma unroll
        for (int rg = 0; rg < 4; ++rg) {
            const int n = n0 + wv * 16 + lg * 4 + rg;
            Zpart[ks * 16384 + n] = Zp[rg];
            S1part[ks * 16384 + n] = S1p[rg];
            dmpart[ks * 16384 + n] = dmin[rg];
            impart[ks * 16384 + n] = imin[rg];
        }
    }
}

__global__ __launch_bounds__(256) void k_rowred(
    const float* __restrict__ Zpart, const float* __restrict__ S1part,
    const float* __restrict__ dmpart, const int* __restrict__ impart,
    float* __restrict__ invZ, int* __restrict__ minidx,
    float* __restrict__ out_idx, double* __restrict__ pse_sum)
{
    const int n = blockIdx.x * 256 + threadIdx.x;
    float Z = __fadd_rn(__fadd_rn(Zpart[n], Zpart[16384 + n]),
                        __fadd_rn(Zpart[32768 + n], Zpart[49152 + n]));
    float S1 = __fadd_rn(__fadd_rn(S1part[n], S1part[16384 + n]),
                         __fadd_rn(S1part[32768 + n], S1part[49152 + n]));
    float dm = dmpart[n];
    int im = impart[n];
#pragma unroll
    for (int ksp = 1; ksp < 4; ++ksp) {
        float d2 = dmpart[ksp * 16384 + n];
        int i2 = impart[ksp * 16384 + n];
        if (d2 < dm || (d2 == dm && i2 < im)) { dm = d2; im = i2; }
    }
    minidx[n] = im;
    out_idx[n] = (float)im;
    float iz = 1.0f / Z;
    invZ[n] = iz;
    double h = log((double)Z) - LN2 * (double)S1 * (double)iz;
#pragma unroll
    for (int m = 32; m > 0; m >>= 1) h += __shfl_xor(h, m, 64);
    if ((threadIdx.x & 63) == 0) atomicAdd(pse_sum, h);
}

// ---- pass 2 (barrier-free): block = k-tile kt (128 codes) x 1024-row n range.
__global__ __launch_bounds__(256) void k_pass2(
    const char* __restrict__ zblob, const char* __restrict__ blob,
    const float* __restrict__ invZ, float* __restrict__ avg_acc)
{
    __shared__ __align__(16) char smem[BLOB_TILE + 4096];
    float* izAll = (float*)(smem + BLOB_TILE);   // [1024] f32

    const int tid = threadIdx.x;
    const int kt = blockIdx.x & 63;
    const int ns = blockIdx.x >> 6;      // 0..15: rows ns*1024 .. +1023
    const int ln = tid & 63, wv = tid >> 6;
    const int lr = ln & 15, lg = ln >> 4;

    STAGE_EMB(smem, kt);
    gload_lds16((const char*)(invZ + ns * 1024) + tid * 16,
                (char*)izAll + (wv << 10));
    __syncthreads();     // only barrier in the kernel

    float e2v[8];
#pragma unroll
    for (int f = 0; f < 8; ++f)
        e2v[f] = *(const float*)(smem + 32768 + (f * 16 + lr) * 4);

    float acck[8] = {0.f, 0.f, 0.f, 0.f, 0.f, 0.f, 0.f, 0.f};

    for (int it = 0; it < 8; ++it) {
        short8v Ah[2][2], Al[2][2];
        const int p64 = ns * 16 + it * 2 + (wv >> 1);
        const char* tb = zblob + (size_t)p64 * 16384;
#pragma unroll
        for (int m = 0; m < 2; ++m) {
            const int rowp = (wv & 1) * 32 + m * 16 + lr;
#pragma unroll
            for (int s = 0; s < 2; ++s) {
                const int byt = rowp * 128 + s * 64 + lg * 16;
                Ah[m][s] = *(const short8v*)(tb + byt);
                Al[m][s] = *(const short8v*)(tb + 8192 + byt);
            }
        }
        const int izb = it * 128 + wv * 32 + lg * 4;
        float4 iz0 = *(const float4*)&izAll[izb];
        float4 iz1 = *(const float4*)&izAll[izb + 16];
        float izr[2][4] = {{iz0.x, iz0.y, iz0.z, iz0.w},
                           {iz1.x, iz1.y, iz1.z, iz1.w}};

        f32x4 acc[2][8];
#pragma unroll
        for (int m = 0; m < 2; ++m)
#pragma unroll
            for (int f = 0; f < 8; ++f) {
                f32x4 zv = {0.f, 0.f, 0.f, 0.f};
                acc[m][f] = zv;
            }

#pragma unroll
        for (int f = 0; f < 8; ++f) {
            const int rr = f * 16 + lr;
            const int sw2 = (rr & 7) << 4;
            short8v Bh[2], Bl[2];
#pragma unroll
            for (int s = 0; s < 2; ++s) {
                const int byt = (rr * 128 + s * 64 + lg * 16) ^ sw2;
                Bh[s] = *(const short8v*)(smem + byt);
                Bl[s] = *(const short8v*)(smem + 16384 + byt);
            }
#pragma unroll
            for (int s = 0; s < 2; ++s)
#pragma unroll
                for (int m = 0; m < 2; ++m) {
                    acc[m][f] = __builtin_amdgcn_mfma_f32_16x16x32_bf16(Ah[m][s], Bh[s], acc[m][f], 0, 0, 0);
                    acc[m][f] = __builtin_amdgcn_mfma_f32_16x16x32_bf16(Ah[m][s], Bl[s], acc[m][f], 0, 0, 0);
                    acc[m][f] = __builtin_amdgcn_mfma_f32_16x16x32_bf16(Al[m][s], Bh[s], acc[m][f], 0, 0, 0);
                    acc[m][f] = __builtin_amdgcn_mfma_f32_16x16x32_bf16(Al[m][s], Bl[s], acc[m][f], 0, 0, 0);
                }
        }

#pragma unroll
        for (int f = 0; f < 8; ++f) {
            const float c2 = e2v[f] * C100L2E;
#pragma unroll
            for (int m = 0; m < 2; ++m)
#pragma unroll
                for (int rg = 0; rg < 4; ++rg) {
                    const float t = fmaf(acc[m][f][rg], C200L2E, -c2);
                    const float ex = __builtin_amdgcn_exp2f(t);
                    acck[f] = fmaf(ex, izr[m][rg], acck[f]);
                }
        }
    }

#pragma unroll
    for (int f = 0; f < 8; ++f) {
        float cs = acck[f];
        cs += __shfl_xor(cs, 16, 64);
        cs += __shfl_xor(cs, 32, 64);
        if (lg == 0) atomicAdd(&avg_acc[kt * 128 + f * 16 + lr], cs);
    }
}

// gather quantized output + per-block loss partial (no contended atomics)
__global__ __launch_bounds__(256) void k_quant(
    const float* __restrict__ z, const float* __restrict__ emb,
    const int* __restrict__ minidx, float* __restrict__ out,
    double* __restrict__ loss_part)
{
    __shared__ float lred[4];
    const int o = blockIdx.x * 256 + threadIdx.x;
    const int n = ((o >> 16) << 10) + (o & 1023);
    const int c = (o >> 10) & 63;
    const int idx = minidx[n];
    const float e = emb[idx * 64 + c];
    const float zv = z[o];
    out[o] = e;
    float d = e - zv;
    float sq = d * d;
#pragma unroll
    for (int m = 32; m > 0; m >>= 1) sq += __shfl_xor(sq, m, 64);
    if ((threadIdx.x & 63) == 0) lred[threadIdx.x >> 6] = sq;
    __syncthreads();
    if (threadIdx.x == 0)
        loss_part[blockIdx.x] = (double)lred[0] + (double)lred[1]
                              + (double)lred[2] + (double)lred[3];
}

__global__ __launch_bounds__(256) void k_final(
    const float* __restrict__ avg_acc, const double* __restrict__ pse_sum,
    const double* __restrict__ loss_part, float* __restrict__ out)
{
    __shared__ double red[256];
    const int tid = threadIdx.x;

    double lsum = 0.0;
    for (int k = tid; k < 4096; k += 256) lsum += loss_part[k];
    red[tid] = lsum;
    __syncthreads();
    for (int s = 128; s > 0; s >>= 1) {
        if (tid < s) red[tid] += red[tid + s];
        __syncthreads();
    }
    double ltot = red[0];
    __syncthreads();

    double local = 0.0;
    for (int k = tid; k < 8192; k += 256) {
        float p = avg_acc[k] * (1.0f / 16384.0f);
        float cl = fmaxf(p, 1e-5f);
        local += (double)(-p * logf(cl));
    }
    red[tid] = local;
    __syncthreads();
    for (int s = 128; s > 0; s >>= 1) {
        if (tid < s) red[tid] += red[tid + s];
        __syncthreads();
    }
    if (tid == 0) {
        double ce = red[0];
        double pse = pse_sum[0] / 16384.0;
        out[1048576] = (float)(1.25 * ltot / 1048576.0);
        out[1048577] = (float)(pse - ce);
    }
}

extern "C" void kernel_launch(void* const* d_in, const int* in_sizes, int n_in,
                              void* d_out, int out_size, void* d_ws, size_t ws_size,
                              hipStream_t stream) {
    const float* z = (const float*)d_in[0];
    const float* emb = (const float*)d_in[1];
    float* out = (float*)d_out;
    char* ws = (char*)d_ws;
    char* blob = ws + OFF_BLOB;
    float* invZ = (float*)(ws + OFF_INVZ);
    int* minidx = (int*)(ws + OFF_MINIDX);
    float* avg_acc = (float*)(ws + OFF_AVG);
    double* pse_sum = (double*)(ws + OFF_PSE);
    float* Zpart = (float*)(ws + OFF_ZPART);
    float* S1part = (float*)(ws + OFF_S1PART);
    float* dmpart = (float*)(ws + OFF_DMPART);
    int* impart = (int*)(ws + OFF_IMPART);
    double* loss_part = (double*)(ws + OFF_LOSSP);
    float* zz = (float*)(ws + OFF_ZZ);
    // z_blob scratch lives in d_out's quantized region (exactly 4 MB);
    // k_quant overwrites it afterwards (stream-ordered).
    char* zblob = (char*)d_out;

    // zero avg_acc + pse_sum every launch (no cross-replay state)
    hipMemsetAsync(ws + OFF_AVG, 0, 32768 + 16, stream);

    k_prep<<<32, 256, 0, stream>>>(emb, blob);
    k_zprep<<<64, 256, 0, stream>>>(z, zblob, zz);
    k_pass1<<<512, 512, 0, stream>>>(zblob, blob, zz, Zpart, S1part, dmpart, impart);
    k_rowred<<<64, 256, 0, stream>>>(Zpart, S1part, dmpart, impart,
                                     invZ, minidx, out + 1048578, pse_sum);
    k_pass2<<<1024, 256, 0, stream>>>(zblob, blob, invZ, avg_acc);
    k_quant<<<4096, 256, 0, stream>>>(z, emb, minidx, out, loss_part);
    k_final<<<1, 256, 0, stream>>>(avg_acc, pse_sum, loss_part, out);
}

// Round 9
// 178.175 us; speedup vs baseline: 5.2734x; 1.0512x over previous
//
#include <hip/hip_runtime.h>
#include <cfloat>

// z:   [16, 64, 32, 32] f32 -> N = 16384 rows of dim 64 (row n = b*1024 + hw)
// emb: [8192, 64] f32
// out (f32): quantized [1048576] | loss [1] | entropy_aux [1] | min_indices [16384]
//
// s = z.e via 4-term bf16-split MFMA (zh+zl)(eh+el), f32 accumulate.
// argmin on numpy-rounding-emulated d = fl(fl(zz+ee) - 2s) (2s exact).
//
// z_blob (bf16 hi/lo A-fragment images, 256 panels x 16KB = 4MB) is written by
// k_prep INTO d_out's quantized region, consumed by k_pass1 and k_pass2;
// k_quant later overwrites that region with the real output (stream-ordered).

typedef __attribute__((ext_vector_type(8))) short short8v;   // 8 bf16
typedef __attribute__((ext_vector_type(4))) float f32x4;

#define C100L2E 144.26950408889634f   // 100*log2(e)
#define C200L2E 288.53900817779268f   // 200*log2(e)
#define LN2 0.6931471805599453

// ws layout (bytes):
#define BLOB_TILE 33792               // 16K hi bf16 + 16K lo bf16 + 512B e2 + 512B c2
#define OFF_BLOB   0                  // 64 tiles * 33792 = 2162688
#define OFF_INVZ   2162688            // f32[16384]
#define OFF_MINIDX 2228224            // i32[16384]
#define OFF_AVG    2293760            // f32[8192]   (zeroed each launch)
#define OFF_PSE    2326528            // double      (zeroed each launch)
#define OFF_ZPART  2326544            // f32[4][16384]
#define OFF_S1PART (OFF_ZPART + 262144)
#define OFF_DMPART (OFF_S1PART + 262144)
#define OFF_IMPART (OFF_DMPART + 262144)
#define OFF_LOSSP  (OFF_IMPART + 262144)  // dbl[4096] fully rewritten each launch
#define OFF_ZZ     (OFF_LOSSP + 32768)    // f32[16384] numpy-pairwise ||z||^2

__device__ __forceinline__ unsigned short f2bf_rne(float f) {
    unsigned u = __float_as_uint(f);
    u = (u + 0x7fffu + ((u >> 16) & 1u)) >> 16;
    return (unsigned short)u;
}

__device__ __forceinline__ void gload_lds16(const void* g, void* l) {
    __builtin_amdgcn_global_load_lds(
        (const __attribute__((address_space(1))) unsigned int*)g,
        (__attribute__((address_space(3))) unsigned int*)l, 16, 0, 0);
}

// Merged prep: blocks 0..31 build emb tile images (+e2 +c2), blocks 32..95
// build the z A-fragment blob + numpy-pairwise ||z||^2.
__global__ __launch_bounds__(256) void k_prep(
    const float* __restrict__ emb, const float* __restrict__ z,
    char* __restrict__ blob, char* __restrict__ zblob, float* __restrict__ zz)
{
    if (blockIdx.x < 32) {
        const int k = blockIdx.x * 256 + threadIdx.x;   // 8192 emb rows
        const float* row = emb + k * 64;
        float fv[64];
#pragma unroll
        for (int i = 0; i < 16; ++i) {
            float4 v = ((const float4*)row)[i];
            fv[4 * i] = v.x; fv[4 * i + 1] = v.y; fv[4 * i + 2] = v.z; fv[4 * i + 3] = v.w;
        }
        float r8[8];
#pragma unroll
        for (int j = 0; j < 8; ++j) r8[j] = __fmul_rn(fv[j], fv[j]);
#pragma unroll
        for (int i = 8; i < 64; i += 8)
#pragma unroll
            for (int j = 0; j < 8; ++j)
                r8[j] = __fadd_rn(r8[j], __fmul_rn(fv[i + j], fv[i + j]));
        float s01 = __fadd_rn(r8[0], r8[1]), s23 = __fadd_rn(r8[2], r8[3]);
        float s45 = __fadd_rn(r8[4], r8[5]), s67 = __fadd_rn(r8[6], r8[7]);
        float e2 = __fadd_rn(__fadd_rn(s01, s23), __fadd_rn(s45, s67));

        char* tb = blob + (size_t)(k >> 7) * BLOB_TILE;
        const int r = k & 127;
        ((float*)(tb + 32768))[r] = e2;
        ((float*)(tb + 33280))[r] = e2 * C100L2E;   // precomputed c2
        const int sw = (r & 7) << 4;
#pragma unroll
        for (int dh = 0; dh < 2; ++dh)
#pragma unroll
            for (int cg = 0; cg < 4; ++cg) {
                short8v hv, lv;
#pragma unroll
                for (int e = 0; e < 8; ++e) {
                    float f = fv[dh * 32 + cg * 8 + e];
                    unsigned short hb = f2bf_rne(f);
                    float hf = __uint_as_float((unsigned)hb << 16);
                    hv[e] = (short)hb;
                    lv[e] = (short)f2bf_rne(f - hf);
                }
                const int byt = (r * 128 + dh * 64 + cg * 16) ^ sw;
                *(short8v*)(tb + byt) = hv;
                *(short8v*)(tb + 16384 + byt) = lv;
            }
    } else {
        const int r = (blockIdx.x - 32) * 256 + threadIdx.x;   // 16384 z rows
        const float* src = z + (r >> 10) * 65536 + (r & 1023);
        float fv[64];
#pragma unroll
        for (int c = 0; c < 64; ++c) fv[c] = src[c * 1024];

        float r8[8];
#pragma unroll
        for (int j = 0; j < 8; ++j) r8[j] = __fmul_rn(fv[j], fv[j]);
#pragma unroll
        for (int i = 8; i < 64; i += 8)
#pragma unroll
            for (int j = 0; j < 8; ++j)
                r8[j] = __fadd_rn(r8[j], __fmul_rn(fv[i + j], fv[i + j]));
        float s01 = __fadd_rn(r8[0], r8[1]), s23 = __fadd_rn(r8[2], r8[3]);
        float s45 = __fadd_rn(r8[4], r8[5]), s67 = __fadd_rn(r8[6], r8[7]);
        zz[r] = __fadd_rn(__fadd_rn(s01, s23), __fadd_rn(s45, s67));

        char* tb = zblob + (size_t)(r >> 6) * 16384;
        const int rowp = r & 63;
#pragma unroll
        for (int cg = 0; cg < 8; ++cg) {
            short8v hv, lv;
#pragma unroll
            for (int e = 0; e < 8; ++e) {
                float f = fv[cg * 8 + e];
                unsigned short hb = f2bf_rne(f);
                float hf = __uint_as_float((unsigned)hb << 16);
                hv[e] = (short)hb;
                lv[e] = (short)f2bf_rne(f - hf);
            }
            *(short8v*)(tb + rowp * 128 + cg * 16) = hv;
            *(short8v*)(tb + 8192 + rowp * 128 + cg * 16) = lv;
        }
    }
}

// stage one 33.8KB emb tile image into LDS, 256-thread version (pass 2)
#define STAGE_EMB(DSTBASE, TILE)                                                  \
    {                                                                             \
        const char* gsrc = blob + (size_t)(TILE) * BLOB_TILE;                     \
        char* ldst = (DSTBASE) + ((tid >> 6) << 10);                              \
        const char* g = gsrc + tid * 16;                                          \
        _Pragma("unroll")                                                         \
        for (int q = 0; q < 8; ++q)                                               \
            gload_lds16(g + q * 4096, ldst + q * 4096);                           \
        if (tid < 64) gload_lds16(gsrc + 32768 + (tid & 63) * 16,                 \
                                  (DSTBASE) + 32768);                             \
    }

// 512-thread version (pass 1): each wave stages its 4KB chunk
#define STAGE512(DSTBASE, TILE)                                                   \
    {                                                                             \
        const char* gsrc = blob + (size_t)(TILE) * BLOB_TILE;                     \
        char* ldst = (DSTBASE) + ((tid >> 6) << 12);                              \
        const char* g = gsrc + ((tid >> 6) << 12) + (tid & 63) * 16;              \
        _Pragma("unroll")                                                         \
        for (int q = 0; q < 4; ++q)                                               \
            gload_lds16(g + q * 1024, ldst + q * 1024);                           \
        if (tid < 64) gload_lds16(gsrc + 32768 + (tid & 63) * 16,                 \
                                  (DSTBASE) + 32768);                             \
    }

// ---- pass 1 v3: 8 waves x 32 rows (m=2), double-buffered emb tiles,
// 1 barrier/iter, per-f interleaved epilogue. B LDS traffic halved vs v2.
__global__ __launch_bounds__(512) void k_pass1(
    const char* __restrict__ zblob, const char* __restrict__ blob,
    const float* __restrict__ zz,
    float* __restrict__ Zpart, float* __restrict__ S1part,
    float* __restrict__ dmpart, int* __restrict__ impart)
{
    __shared__ __align__(16) char smem[2 * BLOB_TILE];

    const int tid = threadIdx.x;
    const int panel = blockIdx.x >> 2;      // 64 panels x 256 rows
    const int ks = blockIdx.x & 3;
    const int n0 = panel * 256;

    const int ln = tid & 63, wv = tid >> 6;
    const int lr = ln & 15, lg = ln >> 4;

    // A-fragments (2 row-tiles of 16) from zblob, registers for whole kernel
    short8v Ah[2][2], Al[2][2];
    {
        const int p64 = (n0 >> 6) + (wv >> 1);
        const char* tb = zblob + (size_t)p64 * 16384;
#pragma unroll
        for (int m = 0; m < 2; ++m) {
            const int rowp = (wv & 1) * 32 + m * 16 + lr;
#pragma unroll
            for (int s = 0; s < 2; ++s) {
                const int byt = rowp * 128 + s * 64 + lg * 16;
                Ah[m][s] = *(const short8v*)(tb + byt);
                Al[m][s] = *(const short8v*)(tb + 8192 + byt);
            }
        }
    }
    float zzr[2][4];
#pragma unroll
    for (int m = 0; m < 2; ++m)
#pragma unroll
        for (int rg = 0; rg < 4; ++rg)
            zzr[m][rg] = zz[n0 + wv * 32 + m * 16 + lg * 4 + rg];

    STAGE512(smem, ks * 16);    // prologue: stage tile 0 into buf 0

    float Zp[2][4], S1p[2][4], dmin[2][4];
    int imin[2][4];
#pragma unroll
    for (int m = 0; m < 2; ++m)
#pragma unroll
        for (int rg = 0; rg < 4; ++rg) {
            Zp[m][rg] = 0.f; S1p[m][rg] = 0.f;
            dmin[m][rg] = FLT_MAX; imin[m][rg] = 0;
        }

    for (int it = 0; it < 16; ++it) {
        const int kbase = ks * 2048 + it * 128;
        __syncthreads();   // buf[it&1] staged (vmcnt drained before barrier)
        const char* bb = smem + (it & 1) * BLOB_TILE;
        if (it < 15) STAGE512(smem + ((it + 1) & 1) * BLOB_TILE, ks * 16 + it + 1);

#pragma unroll
        for (int f = 0; f < 8; ++f) {
            const int rr = f * 16 + lr;
            const int sw2 = (rr & 7) << 4;
            short8v Bh[2], Bl[2];
#pragma unroll
            for (int s = 0; s < 2; ++s) {
                const int byt = (rr * 128 + s * 64 + lg * 16) ^ sw2;
                Bh[s] = *(const short8v*)(bb + byt);
                Bl[s] = *(const short8v*)(bb + 16384 + byt);
            }
            f32x4 a0 = {0.f, 0.f, 0.f, 0.f}, a1 = {0.f, 0.f, 0.f, 0.f};
#pragma unroll
            for (int s = 0; s < 2; ++s) {
                a0 = __builtin_amdgcn_mfma_f32_16x16x32_bf16(Ah[0][s], Bh[s], a0, 0, 0, 0);
                a0 = __builtin_amdgcn_mfma_f32_16x16x32_bf16(Ah[0][s], Bl[s], a0, 0, 0, 0);
                a0 = __builtin_amdgcn_mfma_f32_16x16x32_bf16(Al[0][s], Bh[s], a0, 0, 0, 0);
                a0 = __builtin_amdgcn_mfma_f32_16x16x32_bf16(Al[0][s], Bl[s], a0, 0, 0, 0);
                a1 = __builtin_amdgcn_mfma_f32_16x16x32_bf16(Ah[1][s], Bh[s], a1, 0, 0, 0);
                a1 = __builtin_amdgcn_mfma_f32_16x16x32_bf16(Ah[1][s], Bl[s], a1, 0, 0, 0);
                a1 = __builtin_amdgcn_mfma_f32_16x16x32_bf16(Al[1][s], Bh[s], a1, 0, 0, 0);
                a1 = __builtin_amdgcn_mfma_f32_16x16x32_bf16(Al[1][s], Bl[s], a1, 0, 0, 0);
            }

            const float e2v = *(const float*)(bb + 32768 + (f * 16 + lr) * 4);
            const float c2 = *(const float*)(bb + 33280 + (f * 16 + lr) * 4);
            const int kk = kbase + f * 16 + lr;
#pragma unroll
            for (int m = 0; m < 2; ++m) {
#pragma unroll
                for (int rg = 0; rg < 4; ++rg) {
                    const float sdot = (m == 0) ? a0[rg] : a1[rg];
                    const float t = fmaf(sdot, C200L2E, -c2);
                    const float ex = __builtin_amdgcn_exp2f(t);
                    Zp[m][rg] += ex;
                    S1p[m][rg] = fmaf(t, ex, S1p[m][rg]);
                    const float pre = __fadd_rn(zzr[m][rg], e2v);
                    const float dnp = fmaf(-2.f, sdot, pre);
                    if (dnp < dmin[m][rg]) { dmin[m][rg] = dnp; imin[m][rg] = kk; }
                }
            }
        }
    }

    // reduce across the 16 lr lanes; lex tiebreak (min d, then min idx)
#pragma unroll
    for (int msk = 1; msk < 16; msk <<= 1) {
#pragma unroll
        for (int m = 0; m < 2; ++m)
#pragma unroll
            for (int rg = 0; rg < 4; ++rg) {
                float d2 = __shfl_xor(dmin[m][rg], msk, 16);
                int i2 = __shfl_xor(imin[m][rg], msk, 16);
                float Z2 = __shfl_xor(Zp[m][rg], msk, 16);
                float s2 = __shfl_xor(S1p[m][rg], msk, 16);
                if (d2 < dmin[m][rg] || (d2 == dmin[m][rg] && i2 < imin[m][rg])) {
                    dmin[m][rg] = d2; imin[m][rg] = i2;
                }
                Zp[m][rg] += Z2;
                S1p[m][rg] += s2;
            }
    }
    if (lr == 0) {
#pragma unroll
        for (int m = 0; m < 2; ++m)
#pragma unroll
            for (int rg = 0; rg < 4; ++rg) {
                const int n = n0 + wv * 32 + m * 16 + lg * 4 + rg;
                Zpart[ks * 16384 + n] = Zp[m][rg];
                S1part[ks * 16384 + n] = S1p[m][rg];
                dmpart[ks * 16384 + n] = dmin[m][rg];
                impart[ks * 16384 + n] = imin[m][rg];
            }
    }
}

__global__ __launch_bounds__(256) void k_rowred(
    const float* __restrict__ Zpart, const float* __restrict__ S1part,
    const float* __restrict__ dmpart, const int* __restrict__ impart,
    float* __restrict__ invZ, int* __restrict__ minidx,
    float* __restrict__ out_idx, double* __restrict__ pse_sum)
{
    const int n = blockIdx.x * 256 + threadIdx.x;
    float Z = __fadd_rn(__fadd_rn(Zpart[n], Zpart[16384 + n]),
                        __fadd_rn(Zpart[32768 + n], Zpart[49152 + n]));
    float S1 = __fadd_rn(__fadd_rn(S1part[n], S1part[16384 + n]),
                         __fadd_rn(S1part[32768 + n], S1part[49152 + n]));
    float dm = dmpart[n];
    int im = impart[n];
#pragma unroll
    for (int ksp = 1; ksp < 4; ++ksp) {
        float d2 = dmpart[ksp * 16384 + n];
        int i2 = impart[ksp * 16384 + n];
        if (d2 < dm || (d2 == dm && i2 < im)) { dm = d2; im = i2; }
    }
    minidx[n] = im;
    out_idx[n] = (float)im;
    float iz = 1.0f / Z;
    invZ[n] = iz;
    double h = log((double)Z) - LN2 * (double)S1 * (double)iz;
#pragma unroll
    for (int m = 32; m > 0; m >>= 1) h += __shfl_xor(h, m, 64);
    if ((threadIdx.x & 63) == 0) atomicAdd(pse_sum, h);
}

// ---- pass 2 (barrier-free): block = k-tile kt (128 codes) x 1024-row n range.
__global__ __launch_bounds__(256) void k_pass2(
    const char* __restrict__ zblob, const char* __restrict__ blob,
    const float* __restrict__ invZ, float* __restrict__ avg_acc)
{
    __shared__ __align__(16) char smem[BLOB_TILE + 4096];
    float* izAll = (float*)(smem + BLOB_TILE);   // [1024] f32

    const int tid = threadIdx.x;
    const int kt = blockIdx.x & 63;
    const int ns = blockIdx.x >> 6;      // 0..15: rows ns*1024 .. +1023
    const int ln = tid & 63, wv = tid >> 6;
    const int lr = ln & 15, lg = ln >> 4;

    STAGE_EMB(smem, kt);
    gload_lds16((const char*)(invZ + ns * 1024) + tid * 16,
                (char*)izAll + (wv << 10));
    __syncthreads();     // only barrier in the kernel

    float c2v[8];
#pragma unroll
    for (int f = 0; f < 8; ++f)
        c2v[f] = *(const float*)(smem + 33280 + (f * 16 + lr) * 4);

    float acck[8] = {0.f, 0.f, 0.f, 0.f, 0.f, 0.f, 0.f, 0.f};

    for (int it = 0; it < 8; ++it) {
        short8v Ah[2][2], Al[2][2];
        const int p64 = ns * 16 + it * 2 + (wv >> 1);
        const char* tb = zblob + (size_t)p64 * 16384;
#pragma unroll
        for (int m = 0; m < 2; ++m) {
            const int rowp = (wv & 1) * 32 + m * 16 + lr;
#pragma unroll
            for (int s = 0; s < 2; ++s) {
                const int byt = rowp * 128 + s * 64 + lg * 16;
                Ah[m][s] = *(const short8v*)(tb + byt);
                Al[m][s] = *(const short8v*)(tb + 8192 + byt);
            }
        }
        const int izb = it * 128 + wv * 32 + lg * 4;
        float4 iz0 = *(const float4*)&izAll[izb];
        float4 iz1 = *(const float4*)&izAll[izb + 16];
        float izr[2][4] = {{iz0.x, iz0.y, iz0.z, iz0.w},
                           {iz1.x, iz1.y, iz1.z, iz1.w}};

        f32x4 acc[2][8];
#pragma unroll
        for (int m = 0; m < 2; ++m)
#pragma unroll
            for (int f = 0; f < 8; ++f) {
                f32x4 zv = {0.f, 0.f, 0.f, 0.f};
                acc[m][f] = zv;
            }

#pragma unroll
        for (int f = 0; f < 8; ++f) {
            const int rr = f * 16 + lr;
            const int sw2 = (rr & 7) << 4;
            short8v Bh[2], Bl[2];
#pragma unroll
            for (int s = 0; s < 2; ++s) {
                const int byt = (rr * 128 + s * 64 + lg * 16) ^ sw2;
                Bh[s] = *(const short8v*)(smem + byt);
                Bl[s] = *(const short8v*)(smem + 16384 + byt);
            }
#pragma unroll
            for (int s = 0; s < 2; ++s)
#pragma unroll
                for (int m = 0; m < 2; ++m) {
                    acc[m][f] = __builtin_amdgcn_mfma_f32_16x16x32_bf16(Ah[m][s], Bh[s], acc[m][f], 0, 0, 0);
                    acc[m][f] = __builtin_amdgcn_mfma_f32_16x16x32_bf16(Ah[m][s], Bl[s], acc[m][f], 0, 0, 0);
                    acc[m][f] = __builtin_amdgcn_mfma_f32_16x16x32_bf16(Al[m][s], Bh[s], acc[m][f], 0, 0, 0);
                    acc[m][f] = __builtin_amdgcn_mfma_f32_16x16x32_bf16(Al[m][s], Bl[s], acc[m][f], 0, 0, 0);
                }
        }

#pragma unroll
        for (int f = 0; f < 8; ++f) {
#pragma unroll
            for (int m = 0; m < 2; ++m)
#pragma unroll
                for (int rg = 0; rg < 4; ++rg) {
                    const float t = fmaf(acc[m][f][rg], C200L2E, -c2v[f]);
                    const float ex = __builtin_amdgcn_exp2f(t);
                    acck[f] = fmaf(ex, izr[m][rg], acck[f]);
                }
        }
    }

#pragma unroll
    for (int f = 0; f < 8; ++f) {
        float cs = acck[f];
        cs += __shfl_xor(cs, 16, 64);
        cs += __shfl_xor(cs, 32, 64);
        if (lg == 0) atomicAdd(&avg_acc[kt * 128 + f * 16 + lr], cs);
    }
}

// gather quantized output + per-block loss partial (no contended atomics)
__global__ __launch_bounds__(256) void k_quant(
    const float* __restrict__ z, const float* __restrict__ emb,
    const int* __restrict__ minidx, float* __restrict__ out,
    double* __restrict__ loss_part)
{
    __shared__ float lred[4];
    const int o = blockIdx.x * 256 + threadIdx.x;
    const int n = ((o >> 16) << 10) + (o & 1023);
    const int c = (o >> 10) & 63;
    const int idx = minidx[n];
    const float e = emb[idx * 64 + c];
    const float zv = z[o];
    out[o] = e;
    float d = e - zv;
    float sq = d * d;
#pragma unroll
    for (int m = 32; m > 0; m >>= 1) sq += __shfl_xor(sq, m, 64);
    if ((threadIdx.x & 63) == 0) lred[threadIdx.x >> 6] = sq;
    __syncthreads();
    if (threadIdx.x == 0)
        loss_part[blockIdx.x] = (double)lred[0] + (double)lred[1]
                              + (double)lred[2] + (double)lred[3];
}

__global__ __launch_bounds__(256) void k_final(
    const float* __restrict__ avg_acc, const double* __restrict__ pse_sum,
    const double* __restrict__ loss_part, float* __restrict__ out)
{
    __shared__ double red[256];
    const int tid = threadIdx.x;

    double lsum = 0.0;
    for (int k = tid; k < 4096; k += 256) lsum += loss_part[k];
    red[tid] = lsum;
    __syncthreads();
    for (int s = 128; s > 0; s >>= 1) {
        if (tid < s) red[tid] += red[tid + s];
        __syncthreads();
    }
    double ltot = red[0];
    __syncthreads();

    double local = 0.0;
    for (int k = tid; k < 8192; k += 256) {
        float p = avg_acc[k] * (1.0f / 16384.0f);
        float cl = fmaxf(p, 1e-5f);
        local += (double)(-p * logf(cl));
    }
    red[tid] = local;
    __syncthreads();
    for (int s = 128; s > 0; s >>= 1) {
        if (tid < s) red[tid] += red[tid + s];
        __syncthreads();
    }
    if (tid == 0) {
        double ce = red[0];
        double pse = pse_sum[0] / 16384.0;
        out[1048576] = (float)(1.25 * ltot / 1048576.0);
        out[1048577] = (float)(pse - ce);
    }
}

extern "C" void kernel_launch(void* const* d_in, const int* in_sizes, int n_in,
                              void* d_out, int out_size, void* d_ws, size_t ws_size,
                              hipStream_t stream) {
    const float* z = (const float*)d_in[0];
    const float* emb = (const float*)d_in[1];
    float* out = (float*)d_out;
    char* ws = (char*)d_ws;
    char* blob = ws + OFF_BLOB;
    float* invZ = (float*)(ws + OFF_INVZ);
    int* minidx = (int*)(ws + OFF_MINIDX);
    float* avg_acc = (float*)(ws + OFF_AVG);
    double* pse_sum = (double*)(ws + OFF_PSE);
    float* Zpart = (float*)(ws + OFF_ZPART);
    float* S1part = (float*)(ws + OFF_S1PART);
    float* dmpart = (float*)(ws + OFF_DMPART);
    int* impart = (int*)(ws + OFF_IMPART);
    double* loss_part = (double*)(ws + OFF_LOSSP);
    float* zz = (float*)(ws + OFF_ZZ);
    // z_blob scratch lives in d_out's quantized region (exactly 4 MB);
    // k_quant overwrites it afterwards (stream-ordered).
    char* zblob = (char*)d_out;

    // zero avg_acc + pse_sum every launch (no cross-replay state)
    hipMemsetAsync(ws + OFF_AVG, 0, 32768 + 16, stream);

    k_prep<<<96, 256, 0, stream>>>(emb, z, blob, zblob, zz);
    k_pass1<<<256, 512, 0, stream>>>(zblob, blob, zz, Zpart, S1part, dmpart, impart);
    k_rowred<<<64, 256, 0, stream>>>(Zpart, S1part, dmpart, impart,
                                     invZ, minidx, out + 1048578, pse_sum);
    k_pass2<<<1024, 256, 0, stream>>>(zblob, blob, invZ, avg_acc);
    k_quant<<<4096, 256, 0, stream>>>(z, emb, minidx, out, loss_part);
    k_final<<<1, 256, 0, stream>>>(avg_acc, pse_sum, loss_part, out);
}